// Round 2
// baseline (1222.951 us; speedup 1.0000x reference)
//
#include <hip/hip_runtime.h>
#include <hip/hip_bf16.h>
#include <math.h>

// Problem constants
#define TOKS 16384   // B*N = 8*2048
#define DDIM 256
#define KC   8192
#define KT   32      // number of K tiles (KC/256)

static constexpr float EMA   = 0.99f;
static constexpr float ONE_M = (float)(1.0 - 0.99);      // matches python (1.0-EMA_DECAY) -> f32
static constexpr float EPSF  = 1e-5f;
static constexpr float KEPS  = (float)(8192 * 1e-5);     // K*EPS in f64 -> f32

// ---------------- ws layout (float index) ----------------
#define CS_OFF   0                    // 8192 floats  (cluster_size)
#define SCAL_OFF 8192                 // 16 floats: [0]=loss_sum [1]=n [2]=perp_sum [3]=uniq
#define A_OFF    (8192 + 16)          // 16384 floats (||z_t||^2)
#define B_OFF    (A_OFF + 16384)      // 8192 floats  (||e_k||^2)
#define PD_OFF   (B_OFF + 8192)       // 16384*32 floats (partial min dist)
#define PI_OFF   (PD_OFF + 16384*32)  // 16384*32 ints   (partial argmin)
#define IDX_OFF  (PI_OFF + 16384*32)  // 16384 ints      (final idx)

// ---------------- squared row norms ----------------
__global__ __launch_bounds__(256) void k_sqnorm(const float* __restrict__ x,
                                                float* __restrict__ o) {
  const int lane = threadIdx.x & 63;
  const int row = blockIdx.x * 4 + (threadIdx.x >> 6);
  const float4 v = *reinterpret_cast<const float4*>(x + (size_t)row * DDIM + lane * 4);
  float s = v.x * v.x + v.y * v.y + v.z * v.z + v.w * v.w;
#pragma unroll
  for (int d = 32; d; d >>= 1) s += __shfl_down(s, d);
  if (lane == 0) o[row] = s;
}

// ---------------- tiled distance argmin (partial per K-tile) ----------------
// block: 256 thr; tile 64 tokens x 256 codes; D chunks of 32 in LDS.
// LDS rows are permuted so compute-phase reads are ~conflict-free.
__global__ __launch_bounds__(256) void k_argmin_part(
    const float* __restrict__ z, const float* __restrict__ emb,
    const float* __restrict__ an, const float* __restrict__ bn,
    float* __restrict__ pd, int* __restrict__ pi) {
  __shared__ float zt[64 * 36];    // token row t stored at perm (t&3)*16+(t>>2), stride 36
  __shared__ float et[256 * 36];   // code row k stored at perm (k&15)*16+(k>>4), stride 36

  const int t0 = blockIdx.x * 64;
  const int k0 = blockIdx.y * 256;
  const int tid = threadIdx.x;
  const int cg = tid & 15;   // code group (16 codes each)
  const int tg = tid >> 4;   // token group (4 tokens each)

  float acc[4][16];
#pragma unroll
  for (int i = 0; i < 4; ++i)
#pragma unroll
    for (int j = 0; j < 16; ++j) acc[i][j] = 0.f;

  const int rowb = tid >> 3;
  const int col = (tid & 7) * 4;

  for (int dc = 0; dc < DDIM; dc += 32) {
    // stage z chunk: 64x32
#pragma unroll
    for (int r = 0; r < 2; ++r) {
      const int row = r * 32 + rowb;
      const float4 g = *reinterpret_cast<const float4*>(z + (size_t)(t0 + row) * DDIM + dc + col);
      const int pr = (row & 3) * 16 + (row >> 2);
      *reinterpret_cast<float4*>(zt + pr * 36 + col) = g;
    }
    // stage e chunk: 256x32
#pragma unroll
    for (int r = 0; r < 8; ++r) {
      const int row = r * 32 + rowb;
      const float4 g = *reinterpret_cast<const float4*>(emb + (size_t)(k0 + row) * DDIM + dc + col);
      const int pr = (row & 15) * 16 + (row >> 4);
      *reinterpret_cast<float4*>(et + pr * 36 + col) = g;
    }
    __syncthreads();

#pragma unroll 2
    for (int dj = 0; dj < 32; dj += 4) {
      float4 z4[4];
#pragma unroll
      for (int i = 0; i < 4; ++i)
        z4[i] = *reinterpret_cast<const float4*>(zt + (i * 16 + tg) * 36 + dj);
#pragma unroll
      for (int j = 0; j < 16; ++j) {
        const float4 e4 = *reinterpret_cast<const float4*>(et + (j * 16 + cg) * 36 + dj);
#pragma unroll
        for (int i = 0; i < 4; ++i) {
          acc[i][j] += z4[i].x * e4.x;
          acc[i][j] += z4[i].y * e4.y;
          acc[i][j] += z4[i].z * e4.z;
          acc[i][j] += z4[i].w * e4.w;
        }
      }
    }
    __syncthreads();
  }

  // epilogue: d = fl(fl(a+b) - fl(2*m)) exactly as numpy; argmin with first-index ties
  const int kbase = k0 + cg * 16;
  float bvals[16];
#pragma unroll
  for (int j = 0; j < 16; ++j) bvals[j] = bn[kbase + j];

#pragma unroll
  for (int i = 0; i < 4; ++i) {
    const int t = t0 + tg * 4 + i;
    const float a = an[t];
    float bd = 3.4e38f;
    int bk = 0x7fffffff;
#pragma unroll
    for (int j = 0; j < 16; ++j) {
      const float dist = __fsub_rn(__fadd_rn(a, bvals[j]), __fmul_rn(2.0f, acc[i][j]));
      if (dist < bd) { bd = dist; bk = kbase + j; }
    }
    // reduce across the 16 cg lanes (lanes xor 1,2,4,8 stay in group)
#pragma unroll
    for (int o = 1; o <= 8; o <<= 1) {
      const float od = __shfl_xor(bd, o);
      const int ok = __shfl_xor(bk, o);
      if (od < bd || (od == bd && ok < bk)) { bd = od; bk = ok; }
    }
    if (cg == 0) {
      pd[(size_t)t * KT + blockIdx.y] = bd;
      pi[(size_t)t * KT + blockIdx.y] = bk;
    }
  }
}

// ---------------- final argmin across K tiles ----------------
__global__ __launch_bounds__(256) void k_argmin_final(const float* __restrict__ pd,
                                                      const int* __restrict__ pi,
                                                      float* __restrict__ out_idx,
                                                      int* __restrict__ idx_i) {
  const int t = blockIdx.x * 256 + threadIdx.x;
  float bd = pd[(size_t)t * KT];
  int bk = pi[(size_t)t * KT];
  for (int i = 1; i < KT; ++i) {
    const float d = pd[(size_t)t * KT + i];
    const int k = pi[(size_t)t * KT + i];
    if (d < bd || (d == bd && k < bk)) { bd = d; bk = k; }
  }
  out_idx[t] = (float)bk;
  idx_i[t] = bk;
}

// ---------------- out8 init: 0.99 * ema_w ----------------
__global__ __launch_bounds__(256) void k_scale_ema(const float* __restrict__ ema_w,
                                                   float* __restrict__ o8) {
  const size_t i = ((size_t)blockIdx.x * 256 + threadIdx.x) * 4;
  const float4 v = *reinterpret_cast<const float4*>(ema_w + i);
  float4 r;
  r.x = EMA * v.x; r.y = EMA * v.y; r.z = EMA * v.z; r.w = EMA * v.w;
  *reinterpret_cast<float4*>(o8 + i) = r;
}

// ---------------- quantize: z_q_out, loss, cluster counts, dw scatter ----------------
__global__ __launch_bounds__(256) void k_quant(const float* __restrict__ z,
                                               const float* __restrict__ emb,
                                               const int* __restrict__ idx_i,
                                               float* __restrict__ o0,
                                               float* __restrict__ o8,
                                               float* __restrict__ cs,
                                               float* __restrict__ scal) {
  const int t = blockIdx.x;
  const int d = threadIdx.x;
  const int k = idx_i[t];
  const float zv = z[(size_t)t * DDIM + d];
  const float ev = emb[(size_t)k * DDIM + d];
  // straight-through value, replicating fl(z + fl(z_q - z))
  o0[(size_t)t * DDIM + d] = __fadd_rn(zv, __fsub_rn(ev, zv));
  const float df = __fsub_rn(zv, ev);
  float sq = df * df;
#pragma unroll
  for (int o = 32; o; o >>= 1) sq += __shfl_down(sq, o);
  __shared__ float wsum[4];
  if ((threadIdx.x & 63) == 0) wsum[threadIdx.x >> 6] = sq;
  __syncthreads();
  if (threadIdx.x == 0) {
    atomicAdd(scal + 0, wsum[0] + wsum[1] + wsum[2] + wsum[3]);
    atomicAdd(cs + k, 1.0f);
  }
  unsafeAtomicAdd(o8 + (size_t)k * DDIM + d, ONE_M * zv);
}

// ---------------- per-code stats: raw EMA cluster size, usage, n, perplexity ----------------
__global__ __launch_bounds__(256) void k_stats(const float* __restrict__ ecs_in,
                                               const float* __restrict__ cu_in,
                                               const float* __restrict__ cs,
                                               float* __restrict__ o7,
                                               float* __restrict__ o9,
                                               float* __restrict__ scal) {
  const int k = blockIdx.x * 256 + threadIdx.x;
  const float c = cs[k];
  const float raw = EMA * ecs_in[k] + ONE_M * c;
  o7[k] = raw;
  const float ncu = __fadd_rn(cu_in[k], c);
  o9[k] = ncu;
  atomicAdd(scal + 1, raw);                 // n
  const float p = c * (1.0f / 16384.0f);
  atomicAdd(scal + 2, p * logf(p + 1e-10f)); // sum p*log(p+1e-10)
  if (ncu > 0.0f) atomicAdd(scal + 3, 1.0f); // unique codes
}

// ---------------- Laplace smoothing + scalar outputs ----------------
__global__ __launch_bounds__(256) void k_laplace(float* __restrict__ o7,
                                                 const float* __restrict__ scal,
                                                 float* __restrict__ o2,
                                                 float* __restrict__ o3,
                                                 float* __restrict__ o4,
                                                 float* __restrict__ o5) {
  const int k = blockIdx.x * 256 + threadIdx.x;
  const float n = scal[1];
  const float sm = (o7[k] + EPSF) / (n + KEPS) * n;
  o7[k] = sm;
  if (k == 0) {
    const float m = scal[0] * (1.0f / 4194304.0f);  // mean over B*N*D
    o2[0] = 0.25f * m + m;                          // vq_loss (commitment == codebook numerically)
    o3[0] = expf(-scal[2]);                         // perplexity
    o4[0] = scal[3] * (1.0f / 8192.0f);             // usage_ratio
    o5[0] = scal[3];                                // unique_codes
  }
}

// ---------------- new_emb_weight = new_ema_w / clip(new_ecs) ----------------
__global__ __launch_bounds__(256) void k_embup(const float* __restrict__ o8,
                                               const float* __restrict__ o7,
                                               float* __restrict__ o6) {
  const size_t i = ((size_t)blockIdx.x * 256 + threadIdx.x) * 4;
  const int k = (int)(i >> 8);
  const float dnm = fmaxf(o7[k], EPSF);
  const float4 v = *reinterpret_cast<const float4*>(o8 + i);
  float4 r;
  r.x = v.x / dnm; r.y = v.y / dnm; r.z = v.z / dnm; r.w = v.w / dnm;
  *reinterpret_cast<float4*>(o6 + i) = r;
}

extern "C" void kernel_launch(void* const* d_in, const int* in_sizes, int n_in,
                              void* d_out, int out_size, void* d_ws, size_t ws_size,
                              hipStream_t stream) {
  const float* z     = (const float*)d_in[0];  // [16384,256]
  const float* emb   = (const float*)d_in[1];  // [8192,256]
  const float* ecs   = (const float*)d_in[2];  // [8192]
  const float* ema_w = (const float*)d_in[3];  // [8192,256]
  const float* cu    = (const float*)d_in[4];  // [8192]

  float* out = (float*)d_out;
  float* o0 = out;                 // z_q_out       4194304
  float* o1 = o0 + 4194304;        // indices       16384
  float* o2 = o1 + 16384;          // vq_loss       1
  float* o3 = o2 + 1;              // perplexity    1
  float* o4 = o3 + 1;              // usage_ratio   1
  float* o5 = o4 + 1;              // unique_codes  1
  float* o6 = o5 + 1;              // new_emb       2097152
  float* o7 = o6 + 2097152;        // new_ecs       8192
  float* o8 = o7 + 8192;           // new_ema_w     2097152
  float* o9 = o8 + 2097152;        // new_code_usage 8192

  float* w    = (float*)d_ws;
  float* cs   = w + CS_OFF;
  float* scal = w + SCAL_OFF;
  float* an   = w + A_OFF;
  float* bn   = w + B_OFF;
  float* pd   = w + PD_OFF;
  int*   pi   = (int*)(w + PI_OFF);
  int*   idxi = (int*)(w + IDX_OFF);

  // zero cluster-size + scalar accumulators
  hipMemsetAsync(d_ws, 0, (8192 + 16) * sizeof(float), stream);

  k_sqnorm<<<TOKS / 4, 256, 0, stream>>>(z, an);
  k_sqnorm<<<KC / 4, 256, 0, stream>>>(emb, bn);

  k_argmin_part<<<dim3(TOKS / 64, KT), 256, 0, stream>>>(z, emb, an, bn, pd, pi);
  k_argmin_final<<<TOKS / 256, 256, 0, stream>>>(pd, pi, o1, idxi);

  k_scale_ema<<<(KC * DDIM) / 1024, 256, 0, stream>>>(ema_w, o8);
  k_quant<<<TOKS, 256, 0, stream>>>(z, emb, idxi, o0, o8, cs, scal);

  k_stats<<<KC / 256, 256, 0, stream>>>(ecs, cu, cs, o7, o9, scal);
  k_laplace<<<KC / 256, 256, 0, stream>>>(o7, scal, o2, o3, o4, o5);
  k_embup<<<(KC * DDIM) / 1024, 256, 0, stream>>>(o8, o7, o6);
}

// Round 5
// 579.964 us; speedup vs baseline: 2.1087x; 2.1087x over previous
//
#include <hip/hip_runtime.h>
#include <hip/hip_bf16.h>
#include <math.h>

// Problem constants
#define TOKS 16384   // B*N = 8*2048
#define DDIM 256
#define KC   8192

static constexpr float EMA   = 0.99f;
static constexpr float ONE_M = (float)(1.0 - 0.99);
static constexpr float EPSF  = 1e-5f;
static constexpr float KEPS  = (float)(8192 * 1e-5);

// screen params
#define NCHUNK 4
#define CHUNK  2048       // codes per chunk
#define CTILE  32         // code tile per iteration
#define NIT    (CHUNK/CTILE)   // 64
#define CAP    32
#define DELTA  2.0e-4f

// ---------------- ws layout (float index) ----------------
#define CS_OFF    0
#define SCAL_OFF  8192
#define AN_OFF    8208
#define BN_OFF    (AN_OFF + 16384)      // 24592
#define IDX_OFF   (BN_OFF + 8192)       // 32784
#define CNT_OFF   (IDX_OFF + 16384)     // 49168  (4*16384 uint)
#define EB_OFF    (CNT_OFF + 65536)     // 114704 (2M ushort = 1M floats)
#define LISTS_OFF (EB_OFF + 1048576)    // 1163280 (4*16384*32 ushort = 1M floats)
#define WS_NEED_FLOATS (LISTS_OFF + 1048576)   // 2211856 floats ~ 8.44 MiB

typedef __attribute__((ext_vector_type(8))) short bf16x8;
typedef __attribute__((ext_vector_type(4))) float f32x4;

static __device__ inline short f2b(float f) {
  __hip_bfloat16 h = __float2bfloat16(f);
  return *reinterpret_cast<short*>(&h);
}

// ---------------- convert emb -> bf16 ----------------
__global__ __launch_bounds__(256) void k_conv_e(const float* __restrict__ e,
                                                unsigned short* __restrict__ eb) {
  const size_t i = ((size_t)blockIdx.x * 256 + threadIdx.x) * 8;
  const float4 f0 = *reinterpret_cast<const float4*>(e + i);
  const float4 f1 = *reinterpret_cast<const float4*>(e + i + 4);
  bf16x8 v;
  v[0] = f2b(f0.x); v[1] = f2b(f0.y); v[2] = f2b(f0.z); v[3] = f2b(f0.w);
  v[4] = f2b(f1.x); v[5] = f2b(f1.y); v[6] = f2b(f1.z); v[7] = f2b(f1.w);
  *reinterpret_cast<bf16x8*>(eb + i) = v;
}

// ---------------- squared row norms (identical to round 2) ----------------
__global__ __launch_bounds__(256) void k_sqnorm(const float* __restrict__ x,
                                                float* __restrict__ o) {
  const int lane = threadIdx.x & 63;
  const int row = blockIdx.x * 4 + (threadIdx.x >> 6);
  const float4 v = *reinterpret_cast<const float4*>(x + (size_t)row * DDIM + lane * 4);
  float s = v.x * v.x + v.y * v.y + v.z * v.z + v.w * v.w;
#pragma unroll
  for (int d = 32; d; d >>= 1) s += __shfl_down(s, d);
  if (lane == 0) o[row] = s;
}

// ---------------- bf16 MFMA screen ----------------
// grid (128 token-tiles, 4 chunks), block 256 = 4 waves, 32 token rows/wave.
// B tile 32 codes x 256 dims bf16 in LDS, double buffered, XOR-swizzled
// (pre-swizzled global source -> linear LDS write; swizzled ds_read).
__global__ __launch_bounds__(256, 2) void k_screen(
    const float* __restrict__ z, const unsigned short* __restrict__ eb,
    unsigned int* __restrict__ cnt, unsigned short* __restrict__ lists) {
  __shared__ unsigned short Bt[2][32 * 256];   // 2 x 16KB

  const int tid = threadIdx.x;
  const int lane = tid & 63;
  const int w = tid >> 6;
  const int t0 = blockIdx.x * 128;
  const int k0 = blockIdx.y * CHUNK;

  // ---- A fragments in registers: rows t0+w*32+rf*16+(lane&15), k = kk*32+(lane>>4)*8
  bf16x8 a[2][8];
  {
    const int rlo = lane & 15;
    const int khi = (lane >> 4) * 8;
#pragma unroll
    for (int rf = 0; rf < 2; ++rf) {
      const float* zr = z + (size_t)(t0 + w * 32 + rf * 16 + rlo) * DDIM + khi;
#pragma unroll
      for (int kk = 0; kk < 8; ++kk) {
        const float4 f0 = *reinterpret_cast<const float4*>(zr + kk * 32);
        const float4 f1 = *reinterpret_cast<const float4*>(zr + kk * 32 + 4);
        bf16x8 v;
        v[0] = f2b(f0.x); v[1] = f2b(f0.y); v[2] = f2b(f0.z); v[3] = f2b(f0.w);
        v[4] = f2b(f1.x); v[5] = f2b(f1.y); v[6] = f2b(f1.z); v[7] = f2b(f1.w);
        a[rf][kk] = v;
      }
    }
  }

  const char* ebB = reinterpret_cast<const char*>(eb);
  // staging map: c = tid>>3 (code row in tile), s = tid&7 (64B segment)
  const int sc = tid >> 3;
  const int ss = tid & 7;
  const int swz = (sc & 7) << 4;

  // prologue: stage tile 0 into buf 0
  {
    const size_t gbase = (size_t)(k0 + sc) * 512;
    char* dst = reinterpret_cast<char*>(&Bt[0][0]) + sc * 512 + ss * 64;
#pragma unroll
    for (int q = 0; q < 4; ++q) {
      const int xt = ss * 64 + q * 16;
      const uint4 g = *reinterpret_cast<const uint4*>(ebB + gbase + (xt ^ swz));
      *reinterpret_cast<uint4*>(dst + q * 16) = g;
    }
  }
  __syncthreads();

  float rmax[2][4];
#pragma unroll
  for (int rf = 0; rf < 2; ++rf)
#pragma unroll
    for (int r = 0; r < 4; ++r) rmax[rf][r] = -1e30f;

  const int rdlo = (lane & 15);        // code-within-16 for B frags / C cols
  const int rdhi = (lane >> 4) * 16;   // byte offset of k-subrange within 64B
  uint4 g[4];

  for (int ct = 0; ct < NIT; ++ct) {
    const int cur = ct & 1;
    // T14: issue next-tile global loads early
    if (ct + 1 < NIT) {
      const size_t gbase = (size_t)(k0 + (ct + 1) * CTILE + sc) * 512;
#pragma unroll
      for (int q = 0; q < 4; ++q) {
        const int xt = ss * 64 + q * 16;
        g[q] = *reinterpret_cast<const uint4*>(ebB + gbase + (xt ^ swz));
      }
    }

    // ---- compute tile ct
    f32x4 acc[2][2];
#pragma unroll
    for (int rf = 0; rf < 2; ++rf)
#pragma unroll
      for (int cf = 0; cf < 2; ++cf) acc[rf][cf] = (f32x4){0.f, 0.f, 0.f, 0.f};

    const char* bufB = reinterpret_cast<const char*>(&Bt[cur][0]);
#pragma unroll
    for (int kk = 0; kk < 8; ++kk) {
      const int c0l = rdlo;            // cf = 0
      const int c1l = 16 + rdlo;       // cf = 1
      const int off0 = (kk * 64 + rdhi) ^ ((c0l & 7) << 4);
      const int off1 = (kk * 64 + rdhi) ^ ((c1l & 7) << 4);
      const bf16x8 b0 = *reinterpret_cast<const bf16x8*>(bufB + c0l * 512 + off0);
      const bf16x8 b1 = *reinterpret_cast<const bf16x8*>(bufB + c1l * 512 + off1);
      acc[0][0] = __builtin_amdgcn_mfma_f32_16x16x32_bf16(a[0][kk], b0, acc[0][0], 0, 0, 0);
      acc[1][0] = __builtin_amdgcn_mfma_f32_16x16x32_bf16(a[1][kk], b0, acc[1][0], 0, 0, 0);
      acc[0][1] = __builtin_amdgcn_mfma_f32_16x16x32_bf16(a[0][kk], b1, acc[0][1], 0, 0, 0);
      acc[1][1] = __builtin_amdgcn_mfma_f32_16x16x32_bf16(a[1][kk], b1, acc[1][1], 0, 0, 0);
    }

    // ---- row-max + candidate append
    const int kb = k0 + ct * CTILE;
#pragma unroll
    for (int rf = 0; rf < 2; ++rf) {
#pragma unroll
      for (int r = 0; r < 4; ++r) {
        const float v0 = acc[rf][0][r];
        const float v1 = acc[rf][1][r];
        float tm = fmaxf(v0, v1);
#pragma unroll
        for (int o = 1; o <= 8; o <<= 1) tm = fmaxf(tm, __shfl_xor(tm, o));
        const float rm = fmaxf(rmax[rf][r], tm);
        rmax[rf][r] = rm;
        const float th = rm - DELTA;
        if (v0 >= th || v1 >= th) {
          const int t = t0 + w * 32 + rf * 16 + (lane >> 4) * 4 + r;
          if (v0 >= th) {
            const unsigned int o_ = atomicAdd(&cnt[blockIdx.y * TOKS + t], 1u);
            if (o_ < CAP) lists[((size_t)blockIdx.y * TOKS + t) * CAP + o_] =
                (unsigned short)(kb + rdlo);
          }
          if (v1 >= th) {
            const unsigned int o_ = atomicAdd(&cnt[blockIdx.y * TOKS + t], 1u);
            if (o_ < CAP) lists[((size_t)blockIdx.y * TOKS + t) * CAP + o_] =
                (unsigned short)(kb + 16 + rdlo);
          }
        }
      }
    }

    // ---- write next tile, barrier
    if (ct + 1 < NIT) {
      char* dst = reinterpret_cast<char*>(&Bt[cur ^ 1][0]) + sc * 512 + ss * 64;
#pragma unroll
      for (int q = 0; q < 4; ++q) *reinterpret_cast<uint4*>(dst + q * 16) = g[q];
    }
    __syncthreads();
  }
}

// ---------------- exact rescore (bit-identical chain to round-2 kernel) ----------------
__global__ __launch_bounds__(256) void k_rescore(
    const float* __restrict__ z, const float* __restrict__ emb,
    const float* __restrict__ an, const float* __restrict__ bn,
    const unsigned int* __restrict__ cnt, const unsigned short* __restrict__ lists,
    float* __restrict__ out_idx, int* __restrict__ idx_i) {
  __shared__ float zrow[4][256];
  const int w = threadIdx.x >> 6;
  const int lane = threadIdx.x & 63;
  const int t = blockIdx.x * 4 + w;

  const float4 zv = *reinterpret_cast<const float4*>(z + (size_t)t * DDIM + lane * 4);
  *reinterpret_cast<float4*>(&zrow[w][lane * 4]) = zv;
  __syncthreads();

  const float a = an[t];
  unsigned int raw[NCHUNK], c[NCHUNK];
  bool ovf = false;
  int total = 0;
#pragma unroll
  for (int i = 0; i < NCHUNK; ++i) {
    raw[i] = cnt[i * TOKS + t];
    ovf |= (raw[i] > CAP);
    c[i] = raw[i] > CAP ? CAP : raw[i];
    total += (int)c[i];
  }

  float bd = 3.4e38f;
  int bk = 0x7fffffff;

  if (!ovf) {
    for (int base = 0; base < total; base += 64) {
      const int s = base + lane;
      int k = 0;
      bool act = (s < total);
      if (act) {
        int pos = s, ch = 0;
        if (pos >= (int)c[0]) { pos -= c[0]; ch = 1;
          if (pos >= (int)c[1]) { pos -= c[1]; ch = 2;
            if (pos >= (int)c[2]) { pos -= c[2]; ch = 3; } } }
        k = lists[((size_t)ch * TOKS + t) * CAP + pos];
      }
      float m = 0.f;
      const float* er = emb + (size_t)k * DDIM;
      const float* zr = &zrow[w][0];
      for (int d0 = 0; d0 < DDIM; d0 += 4) {
        const float4 e4 = *reinterpret_cast<const float4*>(er + d0);
        m = __fmaf_rn(zr[d0 + 0], e4.x, m);
        m = __fmaf_rn(zr[d0 + 1], e4.y, m);
        m = __fmaf_rn(zr[d0 + 2], e4.z, m);
        m = __fmaf_rn(zr[d0 + 3], e4.w, m);
      }
      const float d = act
          ? __fsub_rn(__fadd_rn(a, bn[k]), __fmul_rn(2.0f, m))
          : 3.4e38f;
      const int kk = act ? k : 0x7fffffff;
      if (d < bd || (d == bd && kk < bk)) { bd = d; bk = kk; }
    }
  } else {
    // deterministic full scan fallback
    for (int kb = 0; kb < KC; kb += 64) {
      const int k = kb + lane;
      float m = 0.f;
      const float* er = emb + (size_t)k * DDIM;
      const float* zr = &zrow[w][0];
      for (int d0 = 0; d0 < DDIM; d0 += 4) {
        const float4 e4 = *reinterpret_cast<const float4*>(er + d0);
        m = __fmaf_rn(zr[d0 + 0], e4.x, m);
        m = __fmaf_rn(zr[d0 + 1], e4.y, m);
        m = __fmaf_rn(zr[d0 + 2], e4.z, m);
        m = __fmaf_rn(zr[d0 + 3], e4.w, m);
      }
      const float d = __fsub_rn(__fadd_rn(a, bn[k]), __fmul_rn(2.0f, m));
      if (d < bd || (d == bd && k < bk)) { bd = d; bk = k; }
    }
  }

#pragma unroll
  for (int o = 32; o; o >>= 1) {
    const float od = __shfl_xor(bd, o);
    const int ok = __shfl_xor(bk, o);
    if (od < bd || (od == bd && ok < bk)) { bd = od; bk = ok; }
  }
  if (lane == 0) { out_idx[t] = (float)bk; idx_i[t] = bk; }
}

// ---------------- epilogue kernels (unchanged from round 2) ----------------
__global__ __launch_bounds__(256) void k_scale_ema(const float* __restrict__ ema_w,
                                                   float* __restrict__ o8) {
  const size_t i = ((size_t)blockIdx.x * 256 + threadIdx.x) * 4;
  const float4 v = *reinterpret_cast<const float4*>(ema_w + i);
  float4 r;
  r.x = EMA * v.x; r.y = EMA * v.y; r.z = EMA * v.z; r.w = EMA * v.w;
  *reinterpret_cast<float4*>(o8 + i) = r;
}

__global__ __launch_bounds__(256) void k_quant(const float* __restrict__ z,
                                               const float* __restrict__ emb,
                                               const int* __restrict__ idx_i,
                                               float* __restrict__ o0,
                                               float* __restrict__ o8,
                                               float* __restrict__ cs,
                                               float* __restrict__ scal) {
  const int t = blockIdx.x;
  const int d = threadIdx.x;
  const int k = idx_i[t];
  const float zv = z[(size_t)t * DDIM + d];
  const float ev = emb[(size_t)k * DDIM + d];
  o0[(size_t)t * DDIM + d] = __fadd_rn(zv, __fsub_rn(ev, zv));
  const float df = __fsub_rn(zv, ev);
  float sq = df * df;
#pragma unroll
  for (int o = 32; o; o >>= 1) sq += __shfl_down(sq, o);
  __shared__ float wsum[4];
  if ((threadIdx.x & 63) == 0) wsum[threadIdx.x >> 6] = sq;
  __syncthreads();
  if (threadIdx.x == 0) {
    atomicAdd(scal + 0, wsum[0] + wsum[1] + wsum[2] + wsum[3]);
    atomicAdd(cs + k, 1.0f);
  }
  unsafeAtomicAdd(o8 + (size_t)k * DDIM + d, ONE_M * zv);
}

__global__ __launch_bounds__(256) void k_stats(const float* __restrict__ ecs_in,
                                               const float* __restrict__ cu_in,
                                               const float* __restrict__ cs,
                                               float* __restrict__ o7,
                                               float* __restrict__ o9,
                                               float* __restrict__ scal) {
  const int k = blockIdx.x * 256 + threadIdx.x;
  const float cc = cs[k];
  const float raw = EMA * ecs_in[k] + ONE_M * cc;
  o7[k] = raw;
  const float ncu = __fadd_rn(cu_in[k], cc);
  o9[k] = ncu;
  atomicAdd(scal + 1, raw);
  const float p = cc * (1.0f / 16384.0f);
  atomicAdd(scal + 2, p * logf(p + 1e-10f));
  if (ncu > 0.0f) atomicAdd(scal + 3, 1.0f);
}

__global__ __launch_bounds__(256) void k_laplace(float* __restrict__ o7,
                                                 const float* __restrict__ scal,
                                                 float* __restrict__ o2,
                                                 float* __restrict__ o3,
                                                 float* __restrict__ o4,
                                                 float* __restrict__ o5) {
  const int k = blockIdx.x * 256 + threadIdx.x;
  const float n = scal[1];
  const float sm = (o7[k] + EPSF) / (n + KEPS) * n;
  o7[k] = sm;
  if (k == 0) {
    const float m = scal[0] * (1.0f / 4194304.0f);
    o2[0] = 0.25f * m + m;
    o3[0] = expf(-scal[2]);
    o4[0] = scal[3] * (1.0f / 8192.0f);
    o5[0] = scal[3];
  }
}

__global__ __launch_bounds__(256) void k_embup(const float* __restrict__ o8,
                                               const float* __restrict__ o7,
                                               float* __restrict__ o6) {
  const size_t i = ((size_t)blockIdx.x * 256 + threadIdx.x) * 4;
  const int k = (int)(i >> 8);
  const float dnm = fmaxf(o7[k], EPSF);
  const float4 v = *reinterpret_cast<const float4*>(o8 + i);
  float4 r;
  r.x = v.x / dnm; r.y = v.y / dnm; r.z = v.z / dnm; r.w = v.w / dnm;
  *reinterpret_cast<float4*>(o6 + i) = r;
}

extern "C" void kernel_launch(void* const* d_in, const int* in_sizes, int n_in,
                              void* d_out, int out_size, void* d_ws, size_t ws_size,
                              hipStream_t stream) {
  const float* z     = (const float*)d_in[0];
  const float* emb   = (const float*)d_in[1];
  const float* ecs   = (const float*)d_in[2];
  const float* ema_w = (const float*)d_in[3];
  const float* cu    = (const float*)d_in[4];

  float* out = (float*)d_out;
  float* o0 = out;
  float* o1 = o0 + 4194304;
  float* o2 = o1 + 16384;
  float* o3 = o2 + 1;
  float* o4 = o3 + 1;
  float* o5 = o4 + 1;
  float* o6 = o5 + 1;
  float* o7 = o6 + 2097152;
  float* o8 = o7 + 8192;
  float* o9 = o8 + 2097152;

  float* w    = (float*)d_ws;
  float* cs   = w + CS_OFF;
  float* scal = w + SCAL_OFF;
  float* an   = w + AN_OFF;
  float* bn   = w + BN_OFF;
  int*   idxi = (int*)(w + IDX_OFF);
  unsigned int*   cnt   = (unsigned int*)(w + CNT_OFF);
  unsigned short* eb    = (unsigned short*)(w + EB_OFF);
  unsigned short* lists = (unsigned short*)(w + LISTS_OFF);

  const bool ws_ok = ws_size >= (size_t)WS_NEED_FLOATS * sizeof(float);

  hipMemsetAsync(w + CS_OFF, 0, (8192 + 16) * sizeof(float), stream);
  if (ws_ok) {
    hipMemsetAsync(w + CNT_OFF, 0, (size_t)NCHUNK * TOKS * sizeof(unsigned int), stream);
  } else {
    // force k_rescore's deterministic full-scan path (cnt > CAP for every token)
    hipMemsetAsync(w + CNT_OFF, 0xFF, (size_t)NCHUNK * TOKS * sizeof(unsigned int), stream);
  }

  k_sqnorm<<<TOKS / 4, 256, 0, stream>>>(z, an);
  k_sqnorm<<<KC / 4, 256, 0, stream>>>(emb, bn);

  if (ws_ok) {
    k_conv_e<<<(KC * DDIM) / 2048, 256, 0, stream>>>(emb, eb);
    k_screen<<<dim3(TOKS / 128, NCHUNK), 256, 0, stream>>>(z, eb, cnt, lists);
  }
  k_rescore<<<TOKS / 4, 256, 0, stream>>>(z, emb, an, bn, cnt, lists, o1, idxi);

  k_scale_ema<<<(KC * DDIM) / 1024, 256, 0, stream>>>(ema_w, o8);
  k_quant<<<TOKS, 256, 0, stream>>>(z, emb, idxi, o0, o8, cs, scal);

  k_stats<<<KC / 256, 256, 0, stream>>>(ecs, cu, cs, o7, o9, scal);
  k_laplace<<<KC / 256, 256, 0, stream>>>(o7, scal, o2, o3, o4, o5);
  k_embup<<<(KC * DDIM) / 1024, 256, 0, stream>>>(o8, o7, o6);
}

// Round 6
// 480.772 us; speedup vs baseline: 2.5437x; 1.2063x over previous
//
#include <hip/hip_runtime.h>
#include <hip/hip_bf16.h>
#include <math.h>

// Problem constants
#define TOKS 16384   // B*N = 8*2048
#define DDIM 256
#define KC   8192

static constexpr float EMA   = 0.99f;
static constexpr float ONE_M = (float)(1.0 - 0.99);
static constexpr float EPSF  = 1e-5f;
static constexpr float KEPS  = (float)(8192 * 1e-5);

// screen params
#define NCH    8          // chunks (blockIdx.y)
#define CHUNK  1024       // codes per chunk
#define CTILE  32         // codes per LDS tile
#define NIT    (CHUNK/CTILE)   // 32
#define CAP    16
#define DELTA  2.0e-4f

// ---------------- ws layout (float index) ----------------
#define CS_OFF    0                      // 8192
#define SCAL_OFF  8192                   // 16
#define AN_OFF    8208                   // 16384
#define BN_OFF    (AN_OFF + 16384)       // 8192
#define IDX_OFF   (BN_OFF + 8192)        // 16384 int
#define CNT_OFF   (IDX_OFF + 16384)      // 16384 uint
#define THR_OFF   (CNT_OFF + 16384)      // 16384
#define RMX_OFF   (THR_OFF + 16384)      // 8*16384
#define EB_OFF    (RMX_OFF + 131072)     // 2M ushort = 1M floats
#define LISTS_OFF (EB_OFF + 1048576)     // 16384*16 ushort = 131072 floats
// total ~1.39M floats ~5.3MB (ws >= 8.44MB proven in round 5)

typedef __attribute__((ext_vector_type(8))) short bf16x8;
typedef __attribute__((ext_vector_type(4))) float f32x4;

static __device__ inline short f2b(float f) {
  __hip_bfloat16 h = __float2bfloat16(f);
  return *reinterpret_cast<short*>(&h);
}

// ---------------- convert emb -> bf16 ----------------
__global__ __launch_bounds__(256) void k_conv_e(const float* __restrict__ e,
                                                unsigned short* __restrict__ eb) {
  const size_t i = ((size_t)blockIdx.x * 256 + threadIdx.x) * 8;
  const float4 f0 = *reinterpret_cast<const float4*>(e + i);
  const float4 f1 = *reinterpret_cast<const float4*>(e + i + 4);
  bf16x8 v;
  v[0] = f2b(f0.x); v[1] = f2b(f0.y); v[2] = f2b(f0.z); v[3] = f2b(f0.w);
  v[4] = f2b(f1.x); v[5] = f2b(f1.y); v[6] = f2b(f1.z); v[7] = f2b(f1.w);
  *reinterpret_cast<bf16x8*>(eb + i) = v;
}

// ---------------- squared row norms ----------------
__global__ __launch_bounds__(256) void k_sqnorm(const float* __restrict__ x,
                                                float* __restrict__ o) {
  const int lane = threadIdx.x & 63;
  const int row = blockIdx.x * 4 + (threadIdx.x >> 6);
  const float4 v = *reinterpret_cast<const float4*>(x + (size_t)row * DDIM + lane * 4);
  float s = v.x * v.x + v.y * v.y + v.z * v.z + v.w * v.w;
#pragma unroll
  for (int d = 32; d; d >>= 1) s += __shfl_down(s, d);
  if (lane == 0) o[row] = s;
}

// ---------------- bf16 MFMA screen: Pass A (row max) / Pass B (collect) ----------------
// grid (TOKS/128, NCH), block 256 = 4 waves, 32 token rows/wave.
// B tile 32 codes x 256 dims bf16 in LDS, double buffered.
// Staging: linear global bytes -> XOR-swizzled LDS dst; reads use same XOR.
// Both write and read are bank-conflict-free (8 lanes per 4-bank group, derived).
template<bool COLLECT>
__global__ __launch_bounds__(256, 4) void k_gemm(
    const float* __restrict__ z, const unsigned short* __restrict__ eb,
    float* __restrict__ rmx, const float* __restrict__ thr,
    unsigned int* __restrict__ cnt, unsigned short* __restrict__ lists) {
  __shared__ unsigned short Bt[2][CTILE * 256];   // 2 x 16KB

  const int tid = threadIdx.x;
  const int lane = tid & 63;
  const int w = tid >> 6;
  const int t0 = blockIdx.x * 128;
  const int k0 = blockIdx.y * CHUNK;

  // ---- A fragments: rows t0+w*32+rf*16+(lane&15), k = kk*32+(lane>>4)*8
  bf16x8 a[2][8];
  {
    const int rlo = lane & 15;
    const int khi = (lane >> 4) * 8;
#pragma unroll
    for (int rf = 0; rf < 2; ++rf) {
      const float* zr = z + (size_t)(t0 + w * 32 + rf * 16 + rlo) * DDIM + khi;
#pragma unroll
      for (int kk = 0; kk < 8; ++kk) {
        const float4 f0 = *reinterpret_cast<const float4*>(zr + kk * 32);
        const float4 f1 = *reinterpret_cast<const float4*>(zr + kk * 32 + 4);
        bf16x8 v;
        v[0] = f2b(f0.x); v[1] = f2b(f0.y); v[2] = f2b(f0.z); v[3] = f2b(f0.w);
        v[4] = f2b(f1.x); v[5] = f2b(f1.y); v[6] = f2b(f1.z); v[7] = f2b(f1.w);
        a[rf][kk] = v;
      }
    }
  }

  // thresholds (Pass B) / running max (Pass A)
  float tr[2][4];
  float rm[2][4];
#pragma unroll
  for (int rf = 0; rf < 2; ++rf)
#pragma unroll
    for (int r = 0; r < 4; ++r) {
      if (COLLECT) tr[rf][r] = thr[t0 + w * 32 + rf * 16 + (lane >> 4) * 4 + r];
      else         rm[rf][r] = -1e30f;
    }

  const char* ebB = reinterpret_cast<const char*>(eb);
  const int sc = tid >> 3;          // code row in tile (0..31)
  const int ss = tid & 7;           // 64B segment (0..7)
  const int swz = (sc & 7) << 4;

  // prologue: stage tile 0 into buf 0 (linear global, swizzled LDS dst)
  {
    const size_t gb = (size_t)(k0 + sc) * 512 + ss * 64;
    char* dst = reinterpret_cast<char*>(&Bt[0][0]) + sc * 512;
#pragma unroll
    for (int q = 0; q < 4; ++q) {
      const uint4 g = *reinterpret_cast<const uint4*>(ebB + gb + q * 16);
      *reinterpret_cast<uint4*>(dst + ((ss * 64 + q * 16) ^ swz)) = g;
    }
  }
  __syncthreads();

  const int rdlo = lane & 15;
  const int rdhi = (lane >> 4) * 16;
  uint4 g[4];

  for (int ct = 0; ct < NIT; ++ct) {
    // issue next-tile global loads early (hide under MFMA)
    if (ct + 1 < NIT) {
      const size_t gb = (size_t)(k0 + (ct + 1) * CTILE + sc) * 512 + ss * 64;
#pragma unroll
      for (int q = 0; q < 4; ++q)
        g[q] = *reinterpret_cast<const uint4*>(ebB + gb + q * 16);
    }

    // ---- compute tile ct: 32 codes x 32 tokens per wave, full K=256
    f32x4 acc[2][2];
#pragma unroll
    for (int rf = 0; rf < 2; ++rf)
#pragma unroll
      for (int cf = 0; cf < 2; ++cf) acc[rf][cf] = (f32x4){0.f, 0.f, 0.f, 0.f};

    const char* buf = reinterpret_cast<const char*>(&Bt[ct & 1][0]);
#pragma unroll
    for (int kk = 0; kk < 8; ++kk) {
      const int off = (kk * 64 + rdhi) ^ ((rdlo & 7) << 4);
      const bf16x8 b0 = *reinterpret_cast<const bf16x8*>(buf + rdlo * 512 + off);
      const bf16x8 b1 = *reinterpret_cast<const bf16x8*>(buf + (16 + rdlo) * 512 + off);
      acc[0][0] = __builtin_amdgcn_mfma_f32_16x16x32_bf16(a[0][kk], b0, acc[0][0], 0, 0, 0);
      acc[1][0] = __builtin_amdgcn_mfma_f32_16x16x32_bf16(a[1][kk], b0, acc[1][0], 0, 0, 0);
      acc[0][1] = __builtin_amdgcn_mfma_f32_16x16x32_bf16(a[0][kk], b1, acc[0][1], 0, 0, 0);
      acc[1][1] = __builtin_amdgcn_mfma_f32_16x16x32_bf16(a[1][kk], b1, acc[1][1], 0, 0, 0);
    }

    if (!COLLECT) {
      // Pass A: pure per-thread running max (v_max3), zero cross-lane work
#pragma unroll
      for (int rf = 0; rf < 2; ++rf)
#pragma unroll
        for (int r = 0; r < 4; ++r)
          rm[rf][r] = fmaxf(fmaxf(acc[rf][0][r], acc[rf][1][r]), rm[rf][r]);
    } else {
      // Pass B: fixed global threshold, rare appends
      const int kb = k0 + ct * CTILE;
#pragma unroll
      for (int rf = 0; rf < 2; ++rf) {
#pragma unroll
        for (int r = 0; r < 4; ++r) {
          const float v0 = acc[rf][0][r];
          const float v1 = acc[rf][1][r];
          const float th = tr[rf][r];
          if (v0 >= th || v1 >= th) {
            const int t = t0 + w * 32 + rf * 16 + (lane >> 4) * 4 + r;
            if (v0 >= th) {
              const unsigned int o_ = atomicAdd(&cnt[t], 1u);
              if (o_ < CAP) lists[(size_t)t * CAP + o_] = (unsigned short)(kb + rdlo);
            }
            if (v1 >= th) {
              const unsigned int o_ = atomicAdd(&cnt[t], 1u);
              if (o_ < CAP) lists[(size_t)t * CAP + o_] = (unsigned short)(kb + 16 + rdlo);
            }
          }
        }
      }
    }

    // write next tile, barrier
    if (ct + 1 < NIT) {
      char* dst = reinterpret_cast<char*>(&Bt[(ct + 1) & 1][0]) + sc * 512;
#pragma unroll
      for (int q = 0; q < 4; ++q)
        *reinterpret_cast<uint4*>(dst + ((ss * 64 + q * 16) ^ swz)) = g[q];
    }
    __syncthreads();
  }

  if (!COLLECT) {
    // one-time cross-lane reduce over the 16 code-lanes
#pragma unroll
    for (int rf = 0; rf < 2; ++rf) {
#pragma unroll
      for (int r = 0; r < 4; ++r) {
        float v = rm[rf][r];
#pragma unroll
        for (int o = 1; o <= 8; o <<= 1) v = fmaxf(v, __shfl_xor(v, o));
        if ((lane & 15) == 0) {
          const int t = t0 + w * 32 + rf * 16 + (lane >> 4) * 4 + r;
          rmx[(size_t)blockIdx.y * TOKS + t] = v;
        }
      }
    }
  }
}

// ---------------- combine chunk maxima -> threshold ----------------
__global__ __launch_bounds__(256) void k_thr(const float* __restrict__ rmx,
                                             float* __restrict__ thr) {
  const int t = blockIdx.x * 256 + threadIdx.x;
  float m = rmx[t];
#pragma unroll
  for (int c = 1; c < NCH; ++c) m = fmaxf(m, rmx[(size_t)c * TOKS + t]);
  thr[t] = m - DELTA;
}

// ---------------- exact rescore: LDS-staged candidates, bit-exact chain ----------------
__global__ __launch_bounds__(256) void k_rescore(
    const float* __restrict__ z, const float* __restrict__ emb,
    const float* __restrict__ an, const float* __restrict__ bn,
    const unsigned int* __restrict__ cnt, const unsigned short* __restrict__ lists,
    float* __restrict__ out_idx, int* __restrict__ idx_i) {
  __shared__ float er[4][CAP][260];   // padded stride: conflict-lite reads
  __shared__ float zr[4][256];
  const int w = threadIdx.x >> 6;
  const int lane = threadIdx.x & 63;
  const int t = blockIdx.x * 4 + w;

  // stage z row (coalesced; broadcast-read later)
  {
    const float4 v = *reinterpret_cast<const float4*>(z + (size_t)t * DDIM + lane * 4);
    *reinterpret_cast<float4*>(&zr[w][lane * 4]) = v;
  }

  const unsigned int nraw = cnt[t];
  const int n = nraw > CAP ? CAP : (int)nraw;
  const float aN = an[t];
  float bd = 3.4e38f;
  int bk = 0x7fffffff;

  if (nraw <= CAP) {
    // stage candidate emb rows coalesced (whole wave per row)
    for (int c = 0; c < n; ++c) {
      const int k = lists[(size_t)t * CAP + c];
      const float4 v = *reinterpret_cast<const float4*>(emb + (size_t)k * DDIM + lane * 4);
      *reinterpret_cast<float4*>(&er[w][c][lane * 4]) = v;
    }
    // exact sequential-FMA chain (ascending d), one candidate per lane
    const bool act = lane < n;
    const int k = act ? (int)lists[(size_t)t * CAP + lane] : 0;
    const float* e = &er[w][act ? lane : 0][0];
    const float* zp = &zr[w][0];
    float m = 0.f;
    for (int d = 0; d < DDIM; d += 4) {
      m = __fmaf_rn(zp[d + 0], e[d + 0], m);
      m = __fmaf_rn(zp[d + 1], e[d + 1], m);
      m = __fmaf_rn(zp[d + 2], e[d + 2], m);
      m = __fmaf_rn(zp[d + 3], e[d + 3], m);
    }
    bd = act ? __fsub_rn(__fadd_rn(aN, bn[k]), __fmul_rn(2.0f, m)) : 3.4e38f;
    bk = act ? k : 0x7fffffff;
  } else {
    // deterministic full-scan fallback (overflow; ~never)
    for (int kb = 0; kb < KC; kb += 64) {
      const int k = kb + lane;
      float m = 0.f;
      const float* erow = emb + (size_t)k * DDIM;
      const float* zp = &zr[w][0];
      for (int d = 0; d < DDIM; d += 4) {
        const float4 e4 = *reinterpret_cast<const float4*>(erow + d);
        m = __fmaf_rn(zp[d + 0], e4.x, m);
        m = __fmaf_rn(zp[d + 1], e4.y, m);
        m = __fmaf_rn(zp[d + 2], e4.z, m);
        m = __fmaf_rn(zp[d + 3], e4.w, m);
      }
      const float d = __fsub_rn(__fadd_rn(aN, bn[k]), __fmul_rn(2.0f, m));
      if (d < bd || (d == bd && k < bk)) { bd = d; bk = k; }
    }
  }

#pragma unroll
  for (int o = 32; o; o >>= 1) {
    const float od = __shfl_xor(bd, o);
    const int ok = __shfl_xor(bk, o);
    if (od < bd || (od == bd && ok < bk)) { bd = od; bk = ok; }
  }
  if (lane == 0) { out_idx[t] = (float)bk; idx_i[t] = bk; }
}

// ---------------- epilogue kernels (unchanged) ----------------
__global__ __launch_bounds__(256) void k_scale_ema(const float* __restrict__ ema_w,
                                                   float* __restrict__ o8) {
  const size_t i = ((size_t)blockIdx.x * 256 + threadIdx.x) * 4;
  const float4 v = *reinterpret_cast<const float4*>(ema_w + i);
  float4 r;
  r.x = EMA * v.x; r.y = EMA * v.y; r.z = EMA * v.z; r.w = EMA * v.w;
  *reinterpret_cast<float4*>(o8 + i) = r;
}

__global__ __launch_bounds__(256) void k_quant(const float* __restrict__ z,
                                               const float* __restrict__ emb,
                                               const int* __restrict__ idx_i,
                                               float* __restrict__ o0,
                                               float* __restrict__ o8,
                                               float* __restrict__ cs,
                                               float* __restrict__ scal) {
  const int t = blockIdx.x;
  const int d = threadIdx.x;
  const int k = idx_i[t];
  const float zv = z[(size_t)t * DDIM + d];
  const float ev = emb[(size_t)k * DDIM + d];
  o0[(size_t)t * DDIM + d] = __fadd_rn(zv, __fsub_rn(ev, zv));
  const float df = __fsub_rn(zv, ev);
  float sq = df * df;
#pragma unroll
  for (int o = 32; o; o >>= 1) sq += __shfl_down(sq, o);
  __shared__ float wsum[4];
  if ((threadIdx.x & 63) == 0) wsum[threadIdx.x >> 6] = sq;
  __syncthreads();
  if (threadIdx.x == 0) {
    atomicAdd(scal + 0, wsum[0] + wsum[1] + wsum[2] + wsum[3]);
    atomicAdd(cs + k, 1.0f);
  }
  unsafeAtomicAdd(o8 + (size_t)k * DDIM + d, ONE_M * zv);
}

__global__ __launch_bounds__(256) void k_stats(const float* __restrict__ ecs_in,
                                               const float* __restrict__ cu_in,
                                               const float* __restrict__ cs,
                                               float* __restrict__ o7,
                                               float* __restrict__ o9,
                                               float* __restrict__ scal) {
  const int k = blockIdx.x * 256 + threadIdx.x;
  const float cc = cs[k];
  const float raw = EMA * ecs_in[k] + ONE_M * cc;
  o7[k] = raw;
  const float ncu = __fadd_rn(cu_in[k], cc);
  o9[k] = ncu;
  atomicAdd(scal + 1, raw);
  const float p = cc * (1.0f / 16384.0f);
  atomicAdd(scal + 2, p * logf(p + 1e-10f));
  if (ncu > 0.0f) atomicAdd(scal + 3, 1.0f);
}

__global__ __launch_bounds__(256) void k_laplace(float* __restrict__ o7,
                                                 const float* __restrict__ scal,
                                                 float* __restrict__ o2,
                                                 float* __restrict__ o3,
                                                 float* __restrict__ o4,
                                                 float* __restrict__ o5) {
  const int k = blockIdx.x * 256 + threadIdx.x;
  const float n = scal[1];
  const float sm = (o7[k] + EPSF) / (n + KEPS) * n;
  o7[k] = sm;
  if (k == 0) {
    const float m = scal[0] * (1.0f / 4194304.0f);
    o2[0] = 0.25f * m + m;
    o3[0] = expf(-scal[2]);
    o4[0] = scal[3] * (1.0f / 8192.0f);
    o5[0] = scal[3];
  }
}

__global__ __launch_bounds__(256) void k_embup(const float* __restrict__ o8,
                                               const float* __restrict__ o7,
                                               float* __restrict__ o6) {
  const size_t i = ((size_t)blockIdx.x * 256 + threadIdx.x) * 4;
  const int k = (int)(i >> 8);
  const float dnm = fmaxf(o7[k], EPSF);
  const float4 v = *reinterpret_cast<const float4*>(o8 + i);
  float4 r;
  r.x = v.x / dnm; r.y = v.y / dnm; r.z = v.z / dnm; r.w = v.w / dnm;
  *reinterpret_cast<float4*>(o6 + i) = r;
}

extern "C" void kernel_launch(void* const* d_in, const int* in_sizes, int n_in,
                              void* d_out, int out_size, void* d_ws, size_t ws_size,
                              hipStream_t stream) {
  const float* z     = (const float*)d_in[0];
  const float* emb   = (const float*)d_in[1];
  const float* ecs   = (const float*)d_in[2];
  const float* ema_w = (const float*)d_in[3];
  const float* cu    = (const float*)d_in[4];

  float* out = (float*)d_out;
  float* o0 = out;
  float* o1 = o0 + 4194304;
  float* o2 = o1 + 16384;
  float* o3 = o2 + 1;
  float* o4 = o3 + 1;
  float* o5 = o4 + 1;
  float* o6 = o5 + 1;
  float* o7 = o6 + 2097152;
  float* o8 = o7 + 8192;
  float* o9 = o8 + 2097152;

  float* w    = (float*)d_ws;
  float* cs   = w + CS_OFF;
  float* scal = w + SCAL_OFF;
  float* an   = w + AN_OFF;
  float* bn   = w + BN_OFF;
  int*   idxi = (int*)(w + IDX_OFF);
  unsigned int*   cnt   = (unsigned int*)(w + CNT_OFF);
  float* thr  = w + THR_OFF;
  float* rmx  = w + RMX_OFF;
  unsigned short* eb    = (unsigned short*)(w + EB_OFF);
  unsigned short* lists = (unsigned short*)(w + LISTS_OFF);

  hipMemsetAsync(w + CS_OFF, 0, (8192 + 16) * sizeof(float), stream);
  hipMemsetAsync(w + CNT_OFF, 0, TOKS * sizeof(unsigned int), stream);

  k_conv_e<<<(KC * DDIM) / 2048, 256, 0, stream>>>(emb, eb);
  k_sqnorm<<<TOKS / 4, 256, 0, stream>>>(z, an);
  k_sqnorm<<<KC / 4, 256, 0, stream>>>(emb, bn);

  k_gemm<false><<<dim3(TOKS / 128, NCH), 256, 0, stream>>>(z, eb, rmx, thr, cnt, lists);
  k_thr<<<TOKS / 256, 256, 0, stream>>>(rmx, thr);
  k_gemm<true><<<dim3(TOKS / 128, NCH), 256, 0, stream>>>(z, eb, rmx, thr, cnt, lists);
  k_rescore<<<TOKS / 4, 256, 0, stream>>>(z, emb, an, bn, cnt, lists, o1, idxi);

  k_scale_ema<<<(KC * DDIM) / 1024, 256, 0, stream>>>(ema_w, o8);
  k_quant<<<TOKS, 256, 0, stream>>>(z, emb, idxi, o0, o8, cs, scal);

  k_stats<<<KC / 256, 256, 0, stream>>>(ecs, cu, cs, o7, o9, scal);
  k_laplace<<<KC / 256, 256, 0, stream>>>(o7, scal, o2, o3, o4, o5);
  k_embup<<<(KC * DDIM) / 1024, 256, 0, stream>>>(o8, o7, o6);
}

// Round 7
// 325.639 us; speedup vs baseline: 3.7555x; 1.4764x over previous
//
#include <hip/hip_runtime.h>
#include <hip/hip_bf16.h>
#include <math.h>

// Problem constants
#define TOKS 16384   // B*N = 8*2048
#define DDIM 256
#define KC   8192

static constexpr float EMA   = 0.99f;
static constexpr float ONE_M = (float)(1.0 - 0.99);
static constexpr float EPSF  = 1e-5f;
static constexpr float KEPS  = (float)(8192 * 1e-5);

// screen params
#define NCH    8          // chunks (blockIdx.y)
#define CHUNK  1024       // codes per chunk
#define CTILE  32         // codes per LDS tile
#define NIT    (CHUNK/CTILE)   // 32
#define CAP    16
#define DELTA  2.0e-4f

// ---------------- ws layout (float index) ----------------
#define CS_OFF    0                      // 8192
#define SCAL_OFF  8192                   // 16
#define AN_OFF    8208                   // 16384
#define BN_OFF    (AN_OFF + 16384)       // 8192
#define IDX_OFF   (BN_OFF + 8192)        // 16384 int
#define CNT_OFF   (IDX_OFF + 16384)      // 16384 uint
#define THR_OFF   (CNT_OFF + 16384)      // 16384
#define RMX_OFF   (THR_OFF + 16384)      // 8*16384
#define EB_OFF    (RMX_OFF + 131072)     // 2M ushort = 1M floats
#define LISTS_OFF (EB_OFF + 1048576)     // 16384*16 ushort = 131072 floats

typedef __attribute__((ext_vector_type(8))) short bf16x8;
typedef __attribute__((ext_vector_type(4))) float f32x4;

static __device__ inline short f2b(float f) {
  __hip_bfloat16 h = __float2bfloat16(f);
  return *reinterpret_cast<short*>(&h);
}

// ---------------- convert emb -> bf16 ----------------
__global__ __launch_bounds__(256) void k_conv_e(const float* __restrict__ e,
                                                unsigned short* __restrict__ eb) {
  const size_t i = ((size_t)blockIdx.x * 256 + threadIdx.x) * 8;
  const float4 f0 = *reinterpret_cast<const float4*>(e + i);
  const float4 f1 = *reinterpret_cast<const float4*>(e + i + 4);
  bf16x8 v;
  v[0] = f2b(f0.x); v[1] = f2b(f0.y); v[2] = f2b(f0.z); v[3] = f2b(f0.w);
  v[4] = f2b(f1.x); v[5] = f2b(f1.y); v[6] = f2b(f1.z); v[7] = f2b(f1.w);
  *reinterpret_cast<bf16x8*>(eb + i) = v;
}

// ---------------- squared row norms ----------------
__global__ __launch_bounds__(256) void k_sqnorm(const float* __restrict__ x,
                                                float* __restrict__ o) {
  const int lane = threadIdx.x & 63;
  const int row = blockIdx.x * 4 + (threadIdx.x >> 6);
  const float4 v = *reinterpret_cast<const float4*>(x + (size_t)row * DDIM + lane * 4);
  float s = v.x * v.x + v.y * v.y + v.z * v.z + v.w * v.w;
#pragma unroll
  for (int d = 32; d; d >>= 1) s += __shfl_down(s, d);
  if (lane == 0) o[row] = s;
}

// ---------------- bf16 MFMA screen: Pass A (row max) / Pass B (collect) ----------------
template<bool COLLECT>
__global__ __launch_bounds__(256, 4) void k_gemm(
    const float* __restrict__ z, const unsigned short* __restrict__ eb,
    float* __restrict__ rmx, const float* __restrict__ thr,
    unsigned int* __restrict__ cnt, unsigned short* __restrict__ lists) {
  __shared__ unsigned short Bt[2][CTILE * 256];   // 2 x 16KB

  const int tid = threadIdx.x;
  const int lane = tid & 63;
  const int w = tid >> 6;
  const int t0 = blockIdx.x * 128;
  const int k0 = blockIdx.y * CHUNK;

  // ---- A fragments: rows t0+w*32+rf*16+(lane&15), k = kk*32+(lane>>4)*8
  bf16x8 a[2][8];
  {
    const int rlo = lane & 15;
    const int khi = (lane >> 4) * 8;
#pragma unroll
    for (int rf = 0; rf < 2; ++rf) {
      const float* zr = z + (size_t)(t0 + w * 32 + rf * 16 + rlo) * DDIM + khi;
#pragma unroll
      for (int kk = 0; kk < 8; ++kk) {
        const float4 f0 = *reinterpret_cast<const float4*>(zr + kk * 32);
        const float4 f1 = *reinterpret_cast<const float4*>(zr + kk * 32 + 4);
        bf16x8 v;
        v[0] = f2b(f0.x); v[1] = f2b(f0.y); v[2] = f2b(f0.z); v[3] = f2b(f0.w);
        v[4] = f2b(f1.x); v[5] = f2b(f1.y); v[6] = f2b(f1.z); v[7] = f2b(f1.w);
        a[rf][kk] = v;
      }
    }
  }

  float tr[2][4];
  float rm[2][4];
#pragma unroll
  for (int rf = 0; rf < 2; ++rf)
#pragma unroll
    for (int r = 0; r < 4; ++r) {
      if (COLLECT) tr[rf][r] = thr[t0 + w * 32 + rf * 16 + (lane >> 4) * 4 + r];
      else         rm[rf][r] = -1e30f;
    }

  const char* ebB = reinterpret_cast<const char*>(eb);
  const int sc = tid >> 3;          // code row in tile (0..31)
  const int ss = tid & 7;           // 64B segment (0..7)
  const int swz = (sc & 7) << 4;

  // prologue: stage tile 0 into buf 0 (linear global, swizzled LDS dst)
  {
    const size_t gb = (size_t)(k0 + sc) * 512 + ss * 64;
    char* dst = reinterpret_cast<char*>(&Bt[0][0]) + sc * 512;
#pragma unroll
    for (int q = 0; q < 4; ++q) {
      const uint4 g = *reinterpret_cast<const uint4*>(ebB + gb + q * 16);
      *reinterpret_cast<uint4*>(dst + ((ss * 64 + q * 16) ^ swz)) = g;
    }
  }
  __syncthreads();

  const int rdlo = lane & 15;
  const int rdhi = (lane >> 4) * 16;
  uint4 g[4];

  for (int ct = 0; ct < NIT; ++ct) {
    if (ct + 1 < NIT) {
      const size_t gb = (size_t)(k0 + (ct + 1) * CTILE + sc) * 512 + ss * 64;
#pragma unroll
      for (int q = 0; q < 4; ++q)
        g[q] = *reinterpret_cast<const uint4*>(ebB + gb + q * 16);
    }

    f32x4 acc[2][2];
#pragma unroll
    for (int rf = 0; rf < 2; ++rf)
#pragma unroll
      for (int cf = 0; cf < 2; ++cf) acc[rf][cf] = (f32x4){0.f, 0.f, 0.f, 0.f};

    const char* buf = reinterpret_cast<const char*>(&Bt[ct & 1][0]);
#pragma unroll
    for (int kk = 0; kk < 8; ++kk) {
      const int off = (kk * 64 + rdhi) ^ ((rdlo & 7) << 4);
      const bf16x8 b0 = *reinterpret_cast<const bf16x8*>(buf + rdlo * 512 + off);
      const bf16x8 b1 = *reinterpret_cast<const bf16x8*>(buf + (16 + rdlo) * 512 + off);
      acc[0][0] = __builtin_amdgcn_mfma_f32_16x16x32_bf16(a[0][kk], b0, acc[0][0], 0, 0, 0);
      acc[1][0] = __builtin_amdgcn_mfma_f32_16x16x32_bf16(a[1][kk], b0, acc[1][0], 0, 0, 0);
      acc[0][1] = __builtin_amdgcn_mfma_f32_16x16x32_bf16(a[0][kk], b1, acc[0][1], 0, 0, 0);
      acc[1][1] = __builtin_amdgcn_mfma_f32_16x16x32_bf16(a[1][kk], b1, acc[1][1], 0, 0, 0);
    }

    if (!COLLECT) {
#pragma unroll
      for (int rf = 0; rf < 2; ++rf)
#pragma unroll
        for (int r = 0; r < 4; ++r)
          rm[rf][r] = fmaxf(fmaxf(acc[rf][0][r], acc[rf][1][r]), rm[rf][r]);
    } else {
      const int kb = k0 + ct * CTILE;
#pragma unroll
      for (int rf = 0; rf < 2; ++rf) {
#pragma unroll
        for (int r = 0; r < 4; ++r) {
          const float v0 = acc[rf][0][r];
          const float v1 = acc[rf][1][r];
          const float th = tr[rf][r];
          if (v0 >= th || v1 >= th) {
            const int t = t0 + w * 32 + rf * 16 + (lane >> 4) * 4 + r;
            if (v0 >= th) {
              const unsigned int o_ = atomicAdd(&cnt[t], 1u);
              if (o_ < CAP) lists[(size_t)t * CAP + o_] = (unsigned short)(kb + rdlo);
            }
            if (v1 >= th) {
              const unsigned int o_ = atomicAdd(&cnt[t], 1u);
              if (o_ < CAP) lists[(size_t)t * CAP + o_] = (unsigned short)(kb + 16 + rdlo);
            }
          }
        }
      }
    }

    if (ct + 1 < NIT) {
      char* dst = reinterpret_cast<char*>(&Bt[(ct + 1) & 1][0]) + sc * 512;
#pragma unroll
      for (int q = 0; q < 4; ++q)
        *reinterpret_cast<uint4*>(dst + ((ss * 64 + q * 16) ^ swz)) = g[q];
    }
    __syncthreads();
  }

  if (!COLLECT) {
#pragma unroll
    for (int rf = 0; rf < 2; ++rf) {
#pragma unroll
      for (int r = 0; r < 4; ++r) {
        float v = rm[rf][r];
#pragma unroll
        for (int o = 1; o <= 8; o <<= 1) v = fmaxf(v, __shfl_xor(v, o));
        if ((lane & 15) == 0) {
          const int t = t0 + w * 32 + rf * 16 + (lane >> 4) * 4 + r;
          rmx[(size_t)blockIdx.y * TOKS + t] = v;
        }
      }
    }
  }
}

// ---------------- combine chunk maxima -> threshold ----------------
__global__ __launch_bounds__(256) void k_thr(const float* __restrict__ rmx,
                                             float* __restrict__ thr) {
  const int t = blockIdx.x * 256 + threadIdx.x;
  float m = rmx[t];
#pragma unroll
  for (int c = 1; c < NCH; ++c) m = fmaxf(m, rmx[(size_t)c * TOKS + t]);
  thr[t] = m - DELTA;
}

// ---------------- exact rescore: LDS-staged candidates, bit-exact chain ----------------
__global__ __launch_bounds__(256) void k_rescore(
    const float* __restrict__ z, const float* __restrict__ emb,
    const float* __restrict__ an, const float* __restrict__ bn,
    const unsigned int* __restrict__ cnt, const unsigned short* __restrict__ lists,
    float* __restrict__ out_idx, int* __restrict__ idx_i) {
  __shared__ float er[4][CAP][260];
  __shared__ float zr[4][256];
  const int w = threadIdx.x >> 6;
  const int lane = threadIdx.x & 63;
  const int t = blockIdx.x * 4 + w;

  {
    const float4 v = *reinterpret_cast<const float4*>(z + (size_t)t * DDIM + lane * 4);
    *reinterpret_cast<float4*>(&zr[w][lane * 4]) = v;
  }

  const unsigned int nraw = cnt[t];
  const int n = nraw > CAP ? CAP : (int)nraw;
  const float aN = an[t];
  float bd = 3.4e38f;
  int bk = 0x7fffffff;

  if (nraw <= CAP) {
    for (int c = 0; c < n; ++c) {
      const int k = lists[(size_t)t * CAP + c];
      const float4 v = *reinterpret_cast<const float4*>(emb + (size_t)k * DDIM + lane * 4);
      *reinterpret_cast<float4*>(&er[w][c][lane * 4]) = v;
    }
    const bool act = lane < n;
    const int k = act ? (int)lists[(size_t)t * CAP + lane] : 0;
    const float* e = &er[w][act ? lane : 0][0];
    const float* zp = &zr[w][0];
    float m = 0.f;
    for (int d = 0; d < DDIM; d += 4) {
      m = __fmaf_rn(zp[d + 0], e[d + 0], m);
      m = __fmaf_rn(zp[d + 1], e[d + 1], m);
      m = __fmaf_rn(zp[d + 2], e[d + 2], m);
      m = __fmaf_rn(zp[d + 3], e[d + 3], m);
    }
    bd = act ? __fsub_rn(__fadd_rn(aN, bn[k]), __fmul_rn(2.0f, m)) : 3.4e38f;
    bk = act ? k : 0x7fffffff;
  } else {
    for (int kb = 0; kb < KC; kb += 64) {
      const int k = kb + lane;
      float m = 0.f;
      const float* erow = emb + (size_t)k * DDIM;
      const float* zp = &zr[w][0];
      for (int d = 0; d < DDIM; d += 4) {
        const float4 e4 = *reinterpret_cast<const float4*>(erow + d);
        m = __fmaf_rn(zp[d + 0], e4.x, m);
        m = __fmaf_rn(zp[d + 1], e4.y, m);
        m = __fmaf_rn(zp[d + 2], e4.z, m);
        m = __fmaf_rn(zp[d + 3], e4.w, m);
      }
      const float d = __fsub_rn(__fadd_rn(aN, bn[k]), __fmul_rn(2.0f, m));
      if (d < bd || (d == bd && k < bk)) { bd = d; bk = k; }
    }
  }

#pragma unroll
  for (int o = 32; o; o >>= 1) {
    const float od = __shfl_xor(bd, o);
    const int ok = __shfl_xor(bk, o);
    if (od < bd || (od == bd && ok < bk)) { bd = od; bk = ok; }
  }
  if (lane == 0) { out_idx[t] = (float)bk; idx_i[t] = bk; }
}

// ---------------- out8 init: 0.99 * ema_w ----------------
__global__ __launch_bounds__(256) void k_scale_ema(const float* __restrict__ ema_w,
                                                   float* __restrict__ o8) {
  const size_t i = ((size_t)blockIdx.x * 256 + threadIdx.x) * 4;
  const float4 v = *reinterpret_cast<const float4*>(ema_w + i);
  float4 r;
  r.x = EMA * v.x; r.y = EMA * v.y; r.z = EMA * v.z; r.w = EMA * v.w;
  *reinterpret_cast<float4*>(o8 + i) = r;
}

// ---------------- quantize: 1024 blocks x 16 tokens; ONE scal atomic per block ----------------
__global__ __launch_bounds__(256) void k_quant(const float* __restrict__ z,
                                               const float* __restrict__ emb,
                                               const int* __restrict__ idx_i,
                                               float* __restrict__ o0,
                                               float* __restrict__ o8,
                                               float* __restrict__ cs,
                                               float* __restrict__ scal) {
  const int w = threadIdx.x >> 6;
  const int lane = threadIdx.x & 63;
  const int tb = blockIdx.x * 16 + w * 4;   // 4 tokens per wave
  float lsum = 0.f;

#pragma unroll
  for (int i = 0; i < 4; ++i) {
    const int t = tb + i;
    const int k = idx_i[t];
    const float4 zv = *reinterpret_cast<const float4*>(z + (size_t)t * DDIM + lane * 4);
    const float4 ev = *reinterpret_cast<const float4*>(emb + (size_t)k * DDIM + lane * 4);
    float4 o;
    o.x = __fadd_rn(zv.x, __fsub_rn(ev.x, zv.x));
    o.y = __fadd_rn(zv.y, __fsub_rn(ev.y, zv.y));
    o.z = __fadd_rn(zv.z, __fsub_rn(ev.z, zv.z));
    o.w = __fadd_rn(zv.w, __fsub_rn(ev.w, zv.w));
    *reinterpret_cast<float4*>(o0 + (size_t)t * DDIM + lane * 4) = o;
    const float dx = __fsub_rn(zv.x, ev.x);
    const float dy = __fsub_rn(zv.y, ev.y);
    const float dz = __fsub_rn(zv.z, ev.z);
    const float dw = __fsub_rn(zv.w, ev.w);
    lsum += dx * dx + dy * dy + dz * dz + dw * dw;
    float* dst = o8 + (size_t)k * DDIM + lane * 4;
    unsafeAtomicAdd(dst + 0, ONE_M * zv.x);
    unsafeAtomicAdd(dst + 1, ONE_M * zv.y);
    unsafeAtomicAdd(dst + 2, ONE_M * zv.z);
    unsafeAtomicAdd(dst + 3, ONE_M * zv.w);
    if (lane == 0) atomicAdd(cs + k, 1.0f);
  }

#pragma unroll
  for (int o = 32; o; o >>= 1) lsum += __shfl_down(lsum, o);
  __shared__ float wsum[4];
  if (lane == 0) wsum[w] = lsum;
  __syncthreads();
  if (threadIdx.x == 0)
    atomicAdd(scal + 0, wsum[0] + wsum[1] + wsum[2] + wsum[3]);
}

// ---------------- per-code stats: block-reduced scalars (3 atomics/block) ----------------
__global__ __launch_bounds__(256) void k_stats(const float* __restrict__ ecs_in,
                                               const float* __restrict__ cu_in,
                                               const float* __restrict__ cs,
                                               float* __restrict__ o7,
                                               float* __restrict__ o9,
                                               float* __restrict__ scal) {
  const int k = blockIdx.x * 256 + threadIdx.x;
  const int w = threadIdx.x >> 6;
  const int lane = threadIdx.x & 63;
  const float cc = cs[k];
  const float raw = EMA * ecs_in[k] + ONE_M * cc;
  o7[k] = raw;
  const float ncu = __fadd_rn(cu_in[k], cc);
  o9[k] = ncu;
  const float p = cc * (1.0f / 16384.0f);
  float s0 = raw;
  float s1 = p * logf(p + 1e-10f);
  float s2 = ncu > 0.0f ? 1.0f : 0.0f;
#pragma unroll
  for (int o = 32; o; o >>= 1) {
    s0 += __shfl_down(s0, o);
    s1 += __shfl_down(s1, o);
    s2 += __shfl_down(s2, o);
  }
  __shared__ float w0[4], w1[4], w2[4];
  if (lane == 0) { w0[w] = s0; w1[w] = s1; w2[w] = s2; }
  __syncthreads();
  if (threadIdx.x == 0) {
    atomicAdd(scal + 1, w0[0] + w0[1] + w0[2] + w0[3]);
    atomicAdd(scal + 2, w1[0] + w1[1] + w1[2] + w1[3]);
    atomicAdd(scal + 3, w2[0] + w2[1] + w2[2] + w2[3]);
  }
}

// ---------------- Laplace smoothing + scalar outputs ----------------
__global__ __launch_bounds__(256) void k_laplace(float* __restrict__ o7,
                                                 const float* __restrict__ scal,
                                                 float* __restrict__ o2,
                                                 float* __restrict__ o3,
                                                 float* __restrict__ o4,
                                                 float* __restrict__ o5) {
  const int k = blockIdx.x * 256 + threadIdx.x;
  const float n = scal[1];
  const float sm = (o7[k] + EPSF) / (n + KEPS) * n;
  o7[k] = sm;
  if (k == 0) {
    const float m = scal[0] * (1.0f / 4194304.0f);
    o2[0] = 0.25f * m + m;
    o3[0] = expf(-scal[2]);
    o4[0] = scal[3] * (1.0f / 8192.0f);
    o5[0] = scal[3];
  }
}

// ---------------- new_emb_weight = new_ema_w / clip(new_ecs) ----------------
__global__ __launch_bounds__(256) void k_embup(const float* __restrict__ o8,
                                               const float* __restrict__ o7,
                                               float* __restrict__ o6) {
  const size_t i = ((size_t)blockIdx.x * 256 + threadIdx.x) * 4;
  const int k = (int)(i >> 8);
  const float dnm = fmaxf(o7[k], EPSF);
  const float4 v = *reinterpret_cast<const float4*>(o8 + i);
  float4 r;
  r.x = v.x / dnm; r.y = v.y / dnm; r.z = v.z / dnm; r.w = v.w / dnm;
  *reinterpret_cast<float4*>(o6 + i) = r;
}

extern "C" void kernel_launch(void* const* d_in, const int* in_sizes, int n_in,
                              void* d_out, int out_size, void* d_ws, size_t ws_size,
                              hipStream_t stream) {
  const float* z     = (const float*)d_in[0];
  const float* emb   = (const float*)d_in[1];
  const float* ecs   = (const float*)d_in[2];
  const float* ema_w = (const float*)d_in[3];
  const float* cu    = (const float*)d_in[4];

  float* out = (float*)d_out;
  float* o0 = out;
  float* o1 = o0 + 4194304;
  float* o2 = o1 + 16384;
  float* o3 = o2 + 1;
  float* o4 = o3 + 1;
  float* o5 = o4 + 1;
  float* o6 = o5 + 1;
  float* o7 = o6 + 2097152;
  float* o8 = o7 + 8192;
  float* o9 = o8 + 2097152;

  float* w    = (float*)d_ws;
  float* cs   = w + CS_OFF;
  float* scal = w + SCAL_OFF;
  float* an   = w + AN_OFF;
  float* bn   = w + BN_OFF;
  int*   idxi = (int*)(w + IDX_OFF);
  unsigned int*   cnt   = (unsigned int*)(w + CNT_OFF);
  float* thr  = w + THR_OFF;
  float* rmx  = w + RMX_OFF;
  unsigned short* eb    = (unsigned short*)(w + EB_OFF);
  unsigned short* lists = (unsigned short*)(w + LISTS_OFF);

  hipMemsetAsync(w + CS_OFF, 0, (8192 + 16) * sizeof(float), stream);
  hipMemsetAsync(w + CNT_OFF, 0, TOKS * sizeof(unsigned int), stream);

  k_conv_e<<<(KC * DDIM) / 2048, 256, 0, stream>>>(emb, eb);
  k_sqnorm<<<TOKS / 4, 256, 0, stream>>>(z, an);
  k_sqnorm<<<KC / 4, 256, 0, stream>>>(emb, bn);

  k_gemm<false><<<dim3(TOKS / 128, NCH), 256, 0, stream>>>(z, eb, rmx, thr, cnt, lists);
  k_thr<<<TOKS / 256, 256, 0, stream>>>(rmx, thr);
  k_gemm<true><<<dim3(TOKS / 128, NCH), 256, 0, stream>>>(z, eb, rmx, thr, cnt, lists);
  k_rescore<<<TOKS / 4, 256, 0, stream>>>(z, emb, an, bn, cnt, lists, o1, idxi);

  k_scale_ema<<<(KC * DDIM) / 1024, 256, 0, stream>>>(ema_w, o8);
  k_quant<<<TOKS / 16, 256, 0, stream>>>(z, emb, idxi, o0, o8, cs, scal);

  k_stats<<<KC / 256, 256, 0, stream>>>(ecs, cu, cs, o7, o9, scal);
  k_laplace<<<KC / 256, 256, 0, stream>>>(o7, scal, o2, o3, o4, o5);
  k_embup<<<(KC * DDIM) / 1024, 256, 0, stream>>>(o8, o7, o6);
}

// Round 9
// 312.533 us; speedup vs baseline: 3.9130x; 1.0419x over previous
//
#include <hip/hip_runtime.h>
#include <hip/hip_bf16.h>
#include <math.h>

// Problem constants
#define TOKS 16384   // B*N = 8*2048
#define DDIM 256
#define KC   8192

static constexpr float EMA   = 0.99f;
static constexpr float ONE_M = (float)(1.0 - 0.99);
static constexpr float EPSF  = 1e-5f;
static constexpr float KEPS  = (float)(8192 * 1e-5);

// screen params
#define NCH    8          // chunks (blockIdx.y)
#define CHUNK  1024       // codes per chunk
#define CTILE  32         // codes per LDS tile
#define NIT    (CHUNK/CTILE)   // 32
#define NTILES (NCH*NIT)       // 256 global tiles
#define CAP    16
#define DELTA  2.0e-4f

// ---------------- ws layout (float index) ----------------
#define CS_OFF    0                      // 8192
#define SCAL_OFF  8192                   // 16
#define AN_OFF    8208                   // 16384
#define BN_OFF    (AN_OFF + 16384)       // 8192
#define IDX_OFF   (BN_OFF + 8192)        // 16384 int
#define CNT_OFF   (IDX_OFF + 16384)      // 16384 uint
#define THR_OFF   (CNT_OFF + 16384)      // 16384
#define RMX_OFF   (THR_OFF + 16384)      // 8*16384
#define EB_OFF    (RMX_OFF + 131072)     // 2M ushort = 1M floats
#define LISTS_OFF (EB_OFF + 1048576)     // 16384*16 ushort = 131072 floats
#define WTM_OFF   (LISTS_OFF + 131072)   // 512 wave-rows * 256 tiles = 131072
// total ~1.52M floats ~5.8MB (ws >= 8.44MB proven in round 5)

typedef __attribute__((ext_vector_type(8))) short bf16x8;
typedef __attribute__((ext_vector_type(4))) float f32x4;

static __device__ inline short f2b(float f) {
  __hip_bfloat16 h = __float2bfloat16(f);
  return *reinterpret_cast<short*>(&h);
}

// ---------------- convert emb -> bf16 ----------------
__global__ __launch_bounds__(256) void k_conv_e(const float* __restrict__ e,
                                                unsigned short* __restrict__ eb) {
  const size_t i = ((size_t)blockIdx.x * 256 + threadIdx.x) * 8;
  const float4 f0 = *reinterpret_cast<const float4*>(e + i);
  const float4 f1 = *reinterpret_cast<const float4*>(e + i + 4);
  bf16x8 v;
  v[0] = f2b(f0.x); v[1] = f2b(f0.y); v[2] = f2b(f0.z); v[3] = f2b(f0.w);
  v[4] = f2b(f1.x); v[5] = f2b(f1.y); v[6] = f2b(f1.z); v[7] = f2b(f1.w);
  *reinterpret_cast<bf16x8*>(eb + i) = v;
}

// ---------------- squared row norms ----------------
__global__ __launch_bounds__(256) void k_sqnorm(const float* __restrict__ x,
                                                float* __restrict__ o) {
  const int lane = threadIdx.x & 63;
  const int row = blockIdx.x * 4 + (threadIdx.x >> 6);
  const float4 v = *reinterpret_cast<const float4*>(x + (size_t)row * DDIM + lane * 4);
  float s = v.x * v.x + v.y * v.y + v.z * v.z + v.w * v.w;
#pragma unroll
  for (int d = 32; d; d >>= 1) s += __shfl_down(s, d);
  if (lane == 0) o[row] = s;
}

// ---------------- bf16 MFMA screen: Pass A (row max) / Pass B (collect) ----------------
// Staging map (conflict-free writes): lane (sc=tid>>3, ss=tid&7) writes chunks
// q=0..3 at pre-XOR byte ss*16 + q*128 of row sc; layout XOR = ((row&7)<<4).
// Phase lanes (8 consecutive) cover 8 distinct 16B slots for both write & read.
template<bool COLLECT>
__global__ __launch_bounds__(256, 4) void k_gemm(
    const float* __restrict__ z, const unsigned short* __restrict__ eb,
    float* __restrict__ rmx, const float* __restrict__ thr,
    unsigned int* __restrict__ cnt, unsigned short* __restrict__ lists,
    float* __restrict__ wtm) {
  __shared__ unsigned short Bt[2][CTILE * 256];   // 2 x 16KB

  const int tid = threadIdx.x;
  const int lane = tid & 63;
  const int w = tid >> 6;
  const int t0 = blockIdx.x * 128;
  const int k0 = blockIdx.y * CHUNK;
  const int wrow = blockIdx.x * 4 + w;   // wave token-row (32 tokens)

  // ---- A fragments: rows t0+w*32+rf*16+(lane&15), k = kk*32+(lane>>4)*8
  bf16x8 a[2][8];
  {
    const int rlo = lane & 15;
    const int khi = (lane >> 4) * 8;
#pragma unroll
    for (int rf = 0; rf < 2; ++rf) {
      const float* zr = z + (size_t)(t0 + w * 32 + rf * 16 + rlo) * DDIM + khi;
#pragma unroll
      for (int kk = 0; kk < 8; ++kk) {
        const float4 f0 = *reinterpret_cast<const float4*>(zr + kk * 32);
        const float4 f1 = *reinterpret_cast<const float4*>(zr + kk * 32 + 4);
        bf16x8 v;
        v[0] = f2b(f0.x); v[1] = f2b(f0.y); v[2] = f2b(f0.z); v[3] = f2b(f0.w);
        v[4] = f2b(f1.x); v[5] = f2b(f1.y); v[6] = f2b(f1.z); v[7] = f2b(f1.w);
        a[rf][kk] = v;
      }
    }
  }

  float tr[2][4];
  float rm[2][4];
  float tmin = 3.4e38f;
#pragma unroll
  for (int rf = 0; rf < 2; ++rf)
#pragma unroll
    for (int r = 0; r < 4; ++r) {
      if (COLLECT) {
        tr[rf][r] = thr[t0 + w * 32 + rf * 16 + (lane >> 4) * 4 + r];
        tmin = fminf(tmin, tr[rf][r]);
      } else {
        rm[rf][r] = -1e30f;
      }
    }
  if (COLLECT) {
    // wave-uniform min threshold
#pragma unroll
    for (int o = 1; o <= 32; o <<= 1) tmin = fminf(tmin, __shfl_xor(tmin, o));
  }

  const char* ebB = reinterpret_cast<const char*>(eb);
  const int sc = tid >> 3;          // code row in tile (0..31)
  const int ss = tid & 7;           // 16B slot (0..7)
  const int swz = (sc & 7) << 4;

  // prologue: stage tile 0 into buf 0
  {
    const size_t gb = (size_t)(k0 + sc) * 512 + ss * 16;
    char* dst = reinterpret_cast<char*>(&Bt[0][0]) + sc * 512;
#pragma unroll
    for (int q = 0; q < 4; ++q) {
      const uint4 g = *reinterpret_cast<const uint4*>(ebB + gb + q * 128);
      *reinterpret_cast<uint4*>(dst + ((ss * 16 + q * 128) ^ swz)) = g;
    }
  }
  __syncthreads();

  const int rdlo = lane & 15;
  const int rdhi = (lane >> 4) * 16;
  uint4 g[4];

  for (int ct = 0; ct < NIT; ++ct) {
    if (ct + 1 < NIT) {
      const size_t gb = (size_t)(k0 + (ct + 1) * CTILE + sc) * 512 + ss * 16;
#pragma unroll
      for (int q = 0; q < 4; ++q)
        g[q] = *reinterpret_cast<const uint4*>(ebB + gb + q * 128);
    }

    bool compute = true;
    if (COLLECT)
      compute = (wtm[(size_t)wrow * NTILES + blockIdx.y * NIT + ct] >= tmin);

    if (compute) {
      f32x4 acc[2][2];
#pragma unroll
      for (int rf = 0; rf < 2; ++rf)
#pragma unroll
        for (int cf = 0; cf < 2; ++cf) acc[rf][cf] = (f32x4){0.f, 0.f, 0.f, 0.f};

      const char* buf = reinterpret_cast<const char*>(&Bt[ct & 1][0]);
#pragma unroll
      for (int kk = 0; kk < 8; ++kk) {
        const int off = (kk * 64 + rdhi) ^ ((rdlo & 7) << 4);
        const bf16x8 b0 = *reinterpret_cast<const bf16x8*>(buf + rdlo * 512 + off);
        const bf16x8 b1 = *reinterpret_cast<const bf16x8*>(buf + (16 + rdlo) * 512 + off);
        acc[0][0] = __builtin_amdgcn_mfma_f32_16x16x32_bf16(a[0][kk], b0, acc[0][0], 0, 0, 0);
        acc[1][0] = __builtin_amdgcn_mfma_f32_16x16x32_bf16(a[1][kk], b0, acc[1][0], 0, 0, 0);
        acc[0][1] = __builtin_amdgcn_mfma_f32_16x16x32_bf16(a[0][kk], b1, acc[0][1], 0, 0, 0);
        acc[1][1] = __builtin_amdgcn_mfma_f32_16x16x32_bf16(a[1][kk], b1, acc[1][1], 0, 0, 0);
      }

      if (!COLLECT) {
        // Pass A: per-thread running max + wave tile-max for Pass-B skipping
        float tm = -1e30f;
#pragma unroll
        for (int rf = 0; rf < 2; ++rf)
#pragma unroll
          for (int r = 0; r < 4; ++r) {
            const float pm = fmaxf(acc[rf][0][r], acc[rf][1][r]);
            rm[rf][r] = fmaxf(rm[rf][r], pm);
            tm = fmaxf(tm, pm);
          }
#pragma unroll
        for (int o = 1; o <= 32; o <<= 1) tm = fmaxf(tm, __shfl_xor(tm, o));
        if (lane == 0) wtm[(size_t)wrow * NTILES + blockIdx.y * NIT + ct] = tm;
      } else {
        const int kb = k0 + ct * CTILE;
#pragma unroll
        for (int rf = 0; rf < 2; ++rf) {
#pragma unroll
          for (int r = 0; r < 4; ++r) {
            const float v0 = acc[rf][0][r];
            const float v1 = acc[rf][1][r];
            const float th = tr[rf][r];
            if (v0 >= th || v1 >= th) {
              const int t = t0 + w * 32 + rf * 16 + (lane >> 4) * 4 + r;
              if (v0 >= th) {
                const unsigned int o_ = atomicAdd(&cnt[t], 1u);
                if (o_ < CAP) lists[(size_t)t * CAP + o_] = (unsigned short)(kb + rdlo);
              }
              if (v1 >= th) {
                const unsigned int o_ = atomicAdd(&cnt[t], 1u);
                if (o_ < CAP) lists[(size_t)t * CAP + o_] = (unsigned short)(kb + 16 + rdlo);
              }
            }
          }
        }
      }
    }

    if (ct + 1 < NIT) {
      char* dst = reinterpret_cast<char*>(&Bt[(ct + 1) & 1][0]) + sc * 512;
#pragma unroll
      for (int q = 0; q < 4; ++q)
        *reinterpret_cast<uint4*>(dst + ((ss * 16 + q * 128) ^ swz)) = g[q];
    }
    __syncthreads();
  }

  if (!COLLECT) {
#pragma unroll
    for (int rf = 0; rf < 2; ++rf) {
#pragma unroll
      for (int r = 0; r < 4; ++r) {
        float v = rm[rf][r];
#pragma unroll
        for (int o = 1; o <= 8; o <<= 1) v = fmaxf(v, __shfl_xor(v, o));
        if ((lane & 15) == 0) {
          const int t = t0 + w * 32 + rf * 16 + (lane >> 4) * 4 + r;
          rmx[(size_t)blockIdx.y * TOKS + t] = v;
        }
      }
    }
  }
}

// ---------------- combine chunk maxima -> threshold ----------------
__global__ __launch_bounds__(256) void k_thr(const float* __restrict__ rmx,
                                             float* __restrict__ thr) {
  const int t = blockIdx.x * 256 + threadIdx.x;
  float m = rmx[t];
#pragma unroll
  for (int c = 1; c < NCH; ++c) m = fmaxf(m, rmx[(size_t)c * TOKS + t]);
  thr[t] = m - DELTA;
}

// ---------------- exact rescore: LDS-staged candidates, bit-exact chain ----------------
__global__ __launch_bounds__(256) void k_rescore(
    const float* __restrict__ z, const float* __restrict__ emb,
    const float* __restrict__ an, const float* __restrict__ bn,
    const unsigned int* __restrict__ cnt, const unsigned short* __restrict__ lists,
    float* __restrict__ out_idx, int* __restrict__ idx_i) {
  __shared__ float er[4][CAP][260];
  __shared__ float zr[4][256];
  const int w = threadIdx.x >> 6;
  const int lane = threadIdx.x & 63;
  const int t = blockIdx.x * 4 + w;

  {
    const float4 v = *reinterpret_cast<const float4*>(z + (size_t)t * DDIM + lane * 4);
    *reinterpret_cast<float4*>(&zr[w][lane * 4]) = v;
  }

  const unsigned int nraw = cnt[t];
  const int n = nraw > CAP ? CAP : (int)nraw;
  const float aN = an[t];
  float bd = 3.4e38f;
  int bk = 0x7fffffff;

  if (nraw <= CAP) {
    for (int c = 0; c < n; ++c) {
      const int k = lists[(size_t)t * CAP + c];
      const float4 v = *reinterpret_cast<const float4*>(emb + (size_t)k * DDIM + lane * 4);
      *reinterpret_cast<float4*>(&er[w][c][lane * 4]) = v;
    }
    const bool act = lane < n;
    const int k = act ? (int)lists[(size_t)t * CAP + lane] : 0;
    const float* e = &er[w][act ? lane : 0][0];
    const float* zp = &zr[w][0];
    float m = 0.f;
    for (int d = 0; d < DDIM; d += 4) {
      m = __fmaf_rn(zp[d + 0], e[d + 0], m);
      m = __fmaf_rn(zp[d + 1], e[d + 1], m);
      m = __fmaf_rn(zp[d + 2], e[d + 2], m);
      m = __fmaf_rn(zp[d + 3], e[d + 3], m);
    }
    bd = act ? __fsub_rn(__fadd_rn(aN, bn[k]), __fmul_rn(2.0f, m)) : 3.4e38f;
    bk = act ? k : 0x7fffffff;
  } else {
    for (int kb = 0; kb < KC; kb += 64) {
      const int k = kb + lane;
      float m = 0.f;
      const float* erow = emb + (size_t)k * DDIM;
      const float* zp = &zr[w][0];
      for (int d = 0; d < DDIM; d += 4) {
        const float4 e4 = *reinterpret_cast<const float4*>(erow + d);
        m = __fmaf_rn(zp[d + 0], e4.x, m);
        m = __fmaf_rn(zp[d + 1], e4.y, m);
        m = __fmaf_rn(zp[d + 2], e4.z, m);
        m = __fmaf_rn(zp[d + 3], e4.w, m);
      }
      const float d = __fsub_rn(__fadd_rn(aN, bn[k]), __fmul_rn(2.0f, m));
      if (d < bd || (d == bd && k < bk)) { bd = d; bk = k; }
    }
  }

#pragma unroll
  for (int o = 32; o; o >>= 1) {
    const float od = __shfl_xor(bd, o);
    const int ok = __shfl_xor(bk, o);
    if (od < bd || (od == bd && ok < bk)) { bd = od; bk = ok; }
  }
  if (lane == 0) { out_idx[t] = (float)bk; idx_i[t] = bk; }
}

// ---------------- out8 init: 0.99 * ema_w ----------------
__global__ __launch_bounds__(256) void k_scale_ema(const float* __restrict__ ema_w,
                                                   float* __restrict__ o8) {
  const size_t i = ((size_t)blockIdx.x * 256 + threadIdx.x) * 4;
  const float4 v = *reinterpret_cast<const float4*>(ema_w + i);
  float4 r;
  r.x = EMA * v.x; r.y = EMA * v.y; r.z = EMA * v.z; r.w = EMA * v.w;
  *reinterpret_cast<float4*>(o8 + i) = r;
}

// ---------------- quantize: 1024 blocks x 16 tokens; ONE scal atomic per block ----------------
__global__ __launch_bounds__(256) void k_quant(const float* __restrict__ z,
                                               const float* __restrict__ emb,
                                               const int* __restrict__ idx_i,
                                               float* __restrict__ o0,
                                               float* __restrict__ o8,
                                               float* __restrict__ cs,
                                               float* __restrict__ scal) {
  const int w = threadIdx.x >> 6;
  const int lane = threadIdx.x & 63;
  const int tb = blockIdx.x * 16 + w * 4;   // 4 tokens per wave
  float lsum = 0.f;

#pragma unroll
  for (int i = 0; i < 4; ++i) {
    const int t = tb + i;
    const int k = idx_i[t];
    const float4 zv = *reinterpret_cast<const float4*>(z + (size_t)t * DDIM + lane * 4);
    const float4 ev = *reinterpret_cast<const float4*>(emb + (size_t)k * DDIM + lane * 4);
    float4 o;
    o.x = __fadd_rn(zv.x, __fsub_rn(ev.x, zv.x));
    o.y = __fadd_rn(zv.y, __fsub_rn(ev.y, zv.y));
    o.z = __fadd_rn(zv.z, __fsub_rn(ev.z, zv.z));
    o.w = __fadd_rn(zv.w, __fsub_rn(ev.w, zv.w));
    *reinterpret_cast<float4*>(o0 + (size_t)t * DDIM + lane * 4) = o;
    const float dx = __fsub_rn(zv.x, ev.x);
    const float dy = __fsub_rn(zv.y, ev.y);
    const float dz = __fsub_rn(zv.z, ev.z);
    const float dw = __fsub_rn(zv.w, ev.w);
    lsum += dx * dx + dy * dy + dz * dz + dw * dw;
    float* dst = o8 + (size_t)k * DDIM + lane * 4;
    unsafeAtomicAdd(dst + 0, ONE_M * zv.x);
    unsafeAtomicAdd(dst + 1, ONE_M * zv.y);
    unsafeAtomicAdd(dst + 2, ONE_M * zv.z);
    unsafeAtomicAdd(dst + 3, ONE_M * zv.w);
    if (lane == 0) atomicAdd(cs + k, 1.0f);
  }

#pragma unroll
  for (int o = 32; o; o >>= 1) lsum += __shfl_down(lsum, o);
  __shared__ float wsum[4];
  if (lane == 0) wsum[w] = lsum;
  __syncthreads();
  if (threadIdx.x == 0)
    atomicAdd(scal + 0, wsum[0] + wsum[1] + wsum[2] + wsum[3]);
}

// ---------------- per-code stats: block-reduced scalars (3 atomics/block) ----------------
__global__ __launch_bounds__(256) void k_stats(const float* __restrict__ ecs_in,
                                               const float* __restrict__ cu_in,
                                               const float* __restrict__ cs,
                                               float* __restrict__ o7,
                                               float* __restrict__ o9,
                                               float* __restrict__ scal) {
  const int k = blockIdx.x * 256 + threadIdx.x;
  const int w = threadIdx.x >> 6;
  const int lane = threadIdx.x & 63;
  const float cc = cs[k];
  const float raw = EMA * ecs_in[k] + ONE_M * cc;
  o7[k] = raw;
  const float ncu = __fadd_rn(cu_in[k], cc);
  o9[k] = ncu;
  const float p = cc * (1.0f / 16384.0f);
  float s0 = raw;
  float s1 = p * logf(p + 1e-10f);
  float s2 = ncu > 0.0f ? 1.0f : 0.0f;
#pragma unroll
  for (int o = 32; o; o >>= 1) {
    s0 += __shfl_down(s0, o);
    s1 += __shfl_down(s1, o);
    s2 += __shfl_down(s2, o);
  }
  __shared__ float w0[4], w1[4], w2[4];
  if (lane == 0) { w0[w] = s0; w1[w] = s1; w2[w] = s2; }
  __syncthreads();
  if (threadIdx.x == 0) {
    atomicAdd(scal + 1, w0[0] + w0[1] + w0[2] + w0[3]);
    atomicAdd(scal + 2, w1[0] + w1[1] + w1[2] + w1[3]);
    atomicAdd(scal + 3, w2[0] + w2[1] + w2[2] + w2[3]);
  }
}

// ---------------- Laplace smoothing + scalar outputs ----------------
__global__ __launch_bounds__(256) void k_laplace(float* __restrict__ o7,
                                                 const float* __restrict__ scal,
                                                 float* __restrict__ o2,
                                                 float* __restrict__ o3,
                                                 float* __restrict__ o4,
                                                 float* __restrict__ o5) {
  const int k = blockIdx.x * 256 + threadIdx.x;
  const float n = scal[1];
  const float sm = (o7[k] + EPSF) / (n + KEPS) * n;
  o7[k] = sm;
  if (k == 0) {
    const float m = scal[0] * (1.0f / 4194304.0f);
    o2[0] = 0.25f * m + m;
    o3[0] = expf(-scal[2]);
    o4[0] = scal[3] * (1.0f / 8192.0f);
    o5[0] = scal[3];
  }
}

// ---------------- new_emb_weight = new_ema_w / clip(new_ecs) ----------------
__global__ __launch_bounds__(256) void k_embup(const float* __restrict__ o8,
                                               const float* __restrict__ o7,
                                               float* __restrict__ o6) {
  const size_t i = ((size_t)blockIdx.x * 256 + threadIdx.x) * 4;
  const int k = (int)(i >> 8);
  const float dnm = fmaxf(o7[k], EPSF);
  const float4 v = *reinterpret_cast<const float4*>(o8 + i);
  float4 r;
  r.x = v.x / dnm; r.y = v.y / dnm; r.z = v.z / dnm; r.w = v.w / dnm;
  *reinterpret_cast<float4*>(o6 + i) = r;
}

extern "C" void kernel_launch(void* const* d_in, const int* in_sizes, int n_in,
                              void* d_out, int out_size, void* d_ws, size_t ws_size,
                              hipStream_t stream) {
  const float* z     = (const float*)d_in[0];
  const float* emb   = (const float*)d_in[1];
  const float* ecs   = (const float*)d_in[2];
  const float* ema_w = (const float*)d_in[3];
  const float* cu    = (const float*)d_in[4];

  float* out = (float*)d_out;
  float* o0 = out;
  float* o1 = o0 + 4194304;
  float* o2 = o1 + 16384;
  float* o3 = o2 + 1;
  float* o4 = o3 + 1;
  float* o5 = o4 + 1;
  float* o6 = o5 + 1;
  float* o7 = o6 + 2097152;
  float* o8 = o7 + 8192;
  float* o9 = o8 + 2097152;

  float* w    = (float*)d_ws;
  float* cs   = w + CS_OFF;
  float* scal = w + SCAL_OFF;
  float* an   = w + AN_OFF;
  float* bn   = w + BN_OFF;
  int*   idxi = (int*)(w + IDX_OFF);
  unsigned int*   cnt   = (unsigned int*)(w + CNT_OFF);
  float* thr  = w + THR_OFF;
  float* rmx  = w + RMX_OFF;
  unsigned short* eb    = (unsigned short*)(w + EB_OFF);
  unsigned short* lists = (unsigned short*)(w + LISTS_OFF);
  float* wtm  = w + WTM_OFF;

  hipMemsetAsync(w + CS_OFF, 0, (8192 + 16) * sizeof(float), stream);
  hipMemsetAsync(w + CNT_OFF, 0, TOKS * sizeof(unsigned int), stream);

  k_conv_e<<<(KC * DDIM) / 2048, 256, 0, stream>>>(emb, eb);
  k_sqnorm<<<TOKS / 4, 256, 0, stream>>>(z, an);
  k_sqnorm<<<KC / 4, 256, 0, stream>>>(emb, bn);

  k_gemm<false><<<dim3(TOKS / 128, NCH), 256, 0, stream>>>(z, eb, rmx, thr, cnt, lists, wtm);
  k_thr<<<TOKS / 256, 256, 0, stream>>>(rmx, thr);
  k_gemm<true><<<dim3(TOKS / 128, NCH), 256, 0, stream>>>(z, eb, rmx, thr, cnt, lists, wtm);
  k_rescore<<<TOKS / 4, 256, 0, stream>>>(z, emb, an, bn, cnt, lists, o1, idxi);

  k_scale_ema<<<(KC * DDIM) / 1024, 256, 0, stream>>>(ema_w, o8);
  k_quant<<<TOKS / 16, 256, 0, stream>>>(z, emb, idxi, o0, o8, cs, scal);

  k_stats<<<KC / 256, 256, 0, stream>>>(ecs, cu, cs, o7, o9, scal);
  k_laplace<<<KC / 256, 256, 0, stream>>>(o7, scal, o2, o3, o4, o5);
  k_embup<<<(KC * DDIM) / 1024, 256, 0, stream>>>(o8, o7, o6);
}